// Round 11
// baseline (418.865 us; speedup 1.0000x reference)
//
#include <hip/hip_runtime.h>
#include <hip/hip_bf16.h>

typedef unsigned short u16;
typedef u16   u16x4  __attribute__((ext_vector_type(4)));
typedef u16   u16x8  __attribute__((ext_vector_type(8)));
typedef float f32x16 __attribute__((ext_vector_type(16)));

// ---------- helpers ----------

__device__ __forceinline__ u16 f2bf(float f) {
    union { float f; unsigned u; } v; v.f = f;
    unsigned u = v.u;
    unsigned r = (u + 0x7fffu + ((u >> 16) & 1u)) >> 16;   // RNE
    return (u16)r;
}
__device__ __forceinline__ float bf2f(u16 u) {
    union { unsigned u; float f; } x; x.u = (unsigned)u << 16; return x.f;
}

// 32x32x16 MFMA (inline asm). A/B: 4 VGPRs = 8 bf16; C/D: 16 f32.
__device__ __forceinline__ void mfma32(f32x16& d, u16x8 a, u16x8 b) {
    asm("v_mfma_f32_32x32x16_bf16 %0, %1, %2, %0" : "+v"(d) : "v"(a), "v"(b));
}

// ---------- unified GEMM: C = A[M,K] * (BT[N,K])^T, bf16 (or f32) in, f32 acc --
// Tile 128x128, BK=64, 256 threads = 4 waves (2x2 of 64x64), 32x32x16 MFMA
// (R10-proven: MfmaUtil 35%, conflicts 3.1e6, 790 TF).
// R11: T14 async-STAGE split — next tile's global loads issued AFTER barrier,
// BEFORE the MFMA cluster; vmcnt drain lands at next iteration's ds_write, so
// HBM latency hides under MFMA (m249: +3%; our stall frac larger).
// NOTE (R6/R8/R10 analysis): global_load_lds LDS image follows the address-
// ordered set, NOT lane order — per-lane source permutation within a coalesced
// set is a no-op; and per-row k-rotation is algebraically illegal for MFMA.
// gload_lds swizzle is closed. Reg-staged LDK=72 is the proven path.
// EPI: 0 = +pe(aux by row&511), bf16 out [.,512]           (staged)
//      3 = bf16 out batched: (bzc<<18) + row*512+col       (staged)
//      5 = QKV scatter by col; V-part written TRANSPOSED   (staged)
//      6 = O scatter: zz=bz+z0 -> (b,h); [8192,4096]       (staged)
//      7 = f32 split-K partial: Cv + (bz<<22) + row*512+col (direct)
// SWZ: 1 = bijective flat XCD remap; 2 = 8x8 supertile-per-XCD (QKV)
// AF32: A operand is f32, cast during staging (no prefetch; Xp only)
// SPLITZ: 1 = C base switch at z1 (EPI3); 2 = A base switch at z1 (EPI6)

#define LDK 72

template<int EPI, int SWZ = 0, bool AF32 = false, int SPLITZ = 0>
__global__ __launch_bounds__(256)
void gemm_bt(const void* __restrict__ Av, const u16* __restrict__ BT,
             void* __restrict__ Cv, const float* __restrict__ aux,
             int lda, int ldb, int K, long sAb, long sBb, int z0,
             const void* __restrict__ Av2, void* __restrict__ Cv2, int z1)
{
    __shared__ u16 smem[2][128 * LDK];   // 36864 B; epilogue cs reuses first 16384 elems
    u16* As = smem[0];
    u16* Bs = smem[1];

    const int tid  = threadIdx.x;
    const int lane = tid & 63;
    const int wid  = tid >> 6;
    const int wm   = wid >> 1, wn = wid & 1;
    const int bz   = blockIdx.z;

    int bx = blockIdx.x, by = blockIdx.y;
    if (SWZ == 1) {
        const int gx = gridDim.x;
        const int n  = gx * gridDim.y;      // must be %8==0
        const int q  = n >> 3;
        int f = by * gx + bx;
        f = (f & 7) * q + (f >> 3);
        bx = f % gx; by = f / gx;
    } else if (SWZ == 2) {                  // 8x8 supertiles, one per XCD
        const int orig = by * gridDim.x + bx;
        const int xcd  = orig & 7;
        const int j    = orig >> 3;
        const int s    = xcd + ((j >> 6) << 3);
        const int t    = j & 63;
        bx = ((s & 7) << 3) + (t & 7);
        by = ((s >> 3) << 3) + (t >> 3);
    }
    const int m0 = bx * 128;
    const int n0 = by * 128;

    const u16* Ab;
    const float* Af = (const float*)Av + (size_t)bz * sAb;
    if (SPLITZ == 2 && bz >= z1)
        Ab = (const u16*)Av2 + (size_t)(bz - z1) * sAb;
    else
        Ab = (const u16*)Av + (size_t)bz * sAb;
    const u16* Bb = BT + (size_t)bz * sBb;

    // C base switch (EPI 3)
    u16* Cb = (u16*)Cv;
    int bzc = bz;
    if (SPLITZ == 1 && bz >= z1) { Cb = (u16*)Cv2; bzc = bz - z1; }

    const int tr = tid >> 3;          // 0..31
    const int tc = (tid & 7) << 3;    // 0..56

    f32x16 acc[2][2];
#pragma unroll
    for (int i = 0; i < 2; ++i)
#pragma unroll
        for (int j = 0; j < 2; ++j)
            acc[i][j] = (f32x16){0.f,0.f,0.f,0.f,0.f,0.f,0.f,0.f,
                                 0.f,0.f,0.f,0.f,0.f,0.f,0.f,0.f};

    // VALU-write -> MFMA-srcC hazard fence
    asm volatile("s_nop 3"
        : "+v"(acc[0][0]), "+v"(acc[0][1]), "+v"(acc[1][0]), "+v"(acc[1][1]));

    const int fr = lane & 31;             // A/B operand row within 32-block
    const int q8 = (lane >> 5) << 3;      // k sub-chunk: 0 or 8

    // T14 prefetch registers (reg path only)
    u16x8 apre[4], bpre[4];
    auto ldtile = [&](int kt) {
#pragma unroll
        for (int j = 0; j < 4; ++j) {
            const int r = tr + 32 * j;
            apre[j] = *(const u16x8*)&Ab[(size_t)(m0 + r) * lda + kt + tc];
            bpre[j] = *(const u16x8*)&Bb[(size_t)(n0 + r) * ldb + kt + tc];
        }
    };
    if (!AF32) ldtile(0);

    for (int kt = 0; kt < K; kt += 64) {
        __syncthreads();
        if (AF32) {
#pragma unroll
            for (int j = 0; j < 4; ++j) {
                const int r = tr + 32 * j;
                const float* pa = &Af[(size_t)(m0 + r) * lda + kt + tc];
                float4 f0 = *(const float4*)pa;
                float4 f1 = *(const float4*)(pa + 4);
                u16x8 w = { f2bf(f0.x), f2bf(f0.y), f2bf(f0.z), f2bf(f0.w),
                            f2bf(f1.x), f2bf(f1.y), f2bf(f1.z), f2bf(f1.w) };
                *(u16x8*)&As[r * LDK + tc] = w;
                *(u16x8*)&Bs[r * LDK + tc] = *(const u16x8*)&Bb[(size_t)(n0 + r) * ldb + kt + tc];
            }
        } else {
#pragma unroll
            for (int j = 0; j < 4; ++j) {
                const int r = tr + 32 * j;
                *(u16x8*)&As[r * LDK + tc] = apre[j];
                *(u16x8*)&Bs[r * LDK + tc] = bpre[j];
            }
        }
        __syncthreads();
        if (!AF32 && kt + 64 < K) ldtile(kt + 64);   // issue-early; drained at next ds_write

#pragma unroll
        for (int ks = 0; ks < 4; ++ks) {
            const int ko = ks * 16 + q8;
            u16x8 a0 = *(const u16x8*)&As[(wm * 64 +      fr) * LDK + ko];
            u16x8 a1 = *(const u16x8*)&As[(wm * 64 + 32 + fr) * LDK + ko];
            u16x8 b0 = *(const u16x8*)&Bs[(wn * 64 +      fr) * LDK + ko];
            u16x8 b1 = *(const u16x8*)&Bs[(wn * 64 + 32 + fr) * LDK + ko];
            mfma32(acc[0][0], a0, b0);
            mfma32(acc[0][1], a0, b1);
            mfma32(acc[1][0], a1, b0);
            mfma32(acc[1][1], a1, b1);
        }
    }

    // MFMA-write -> VALU/VMEM-read hazard fence
    asm volatile("s_nop 7\n\ts_nop 7\n\ts_nop 7"
        : "+v"(acc[0][0]), "+v"(acc[0][1]), "+v"(acc[1][0]), "+v"(acc[1][1]));

    // C/D map (m74/m101): col = lane&31, row = (reg&3) + 8*(reg>>2) + 4*(lane>>5)
    const int lc = lane & 31;
    const int lq = (lane >> 5) << 2;

    if (EPI == 7) {   // direct f32 split-K partial
#pragma unroll
        for (int mi = 0; mi < 2; ++mi)
#pragma unroll
            for (int ni = 0; ni < 2; ++ni)
#pragma unroll
                for (int i = 0; i < 16; ++i) {
                    const int row = m0 + wm * 64 + mi * 32 + (i & 3) + 8 * (i >> 2) + lq;
                    const int col = n0 + wn * 64 + ni * 32 + lc;
                    ((float*)Cv)[((size_t)bz << 22) + (size_t)row * 512 + col] = acc[mi][ni][i];
                }
        return;
    }

    // staged bf16 epilogue via cs[128][128] (XOR-swizzled; R4-proven)
    u16* cs = (u16*)smem;
    auto cswz = [](int r, int c) { return r * 128 + (c ^ (((r >> 3) & 7) << 4)); };
    __syncthreads();
#pragma unroll
    for (int mi = 0; mi < 2; ++mi)
#pragma unroll
        for (int ni = 0; ni < 2; ++ni)
#pragma unroll
            for (int i = 0; i < 16; ++i) {
                const int rl = wm * 64 + mi * 32 + (i & 3) + 8 * (i >> 2) + lq;
                const int cl = wn * 64 + ni * 32 + lc;
                float v = acc[mi][ni][i];
                if (EPI == 0) v += aux[(((m0 + rl) & 511) << 9) + n0 + cl];
                cs[cswz(rl, cl)] = f2bf(v);
            }
    __syncthreads();

    if (EPI == 5 && n0 >= 8192) {
        // V part: write transposed -> VT[h*16+b][e][t]
        const int elq = tid >> 4;          // 0..15
        const int t8  = (tid & 15) << 3;   // 0..120
        const int hh  = (n0 >> 9) & 7;
        const int bb  = m0 >> 9;
        const int e0v = n0 & 511;
        const int t0v = m0 & 511;
        u16* Vbase = (u16*)Cv + 67108864;  // part-2 offset (elements)
#pragma unroll
        for (int q = 0; q < 8; ++q) {
            const int e_loc = q * 16 + elq;
            u16x8 w;
#pragma unroll
            for (int k = 0; k < 8; ++k) w[k] = cs[cswz(t8 + k, e_loc)];
            const size_t dst = ((size_t)(hh * 16 + bb) << 18)
                             + (size_t)(e0v + e_loc) * 512 + t0v + t8;
            *(u16x8*)&Vbase[dst] = w;
        }
        return;
    }

    const int frl = tid >> 4;          // 0..15
    const int fc8 = (tid & 15) << 3;   // 0..120
#pragma unroll
    for (int p = 0; p < 8; ++p) {
        const int rl = p * 16 + frl;
        u16x8 w = *(u16x8*)&cs[rl * 128 + (fc8 ^ (((rl >> 3) & 7) << 4))];
        const int row = m0 + rl;
        const int col = n0 + fc8;
        size_t dst;
        u16* dstp;
        if (EPI == 0) {
            dst = (size_t)row * 512 + col;
            dstp = (u16*)Cv;
        } else if (EPI == 3) {
            dst = ((size_t)bzc << 18) + ((size_t)row << 9) + col;
            dstp = Cb;
        } else if (EPI == 5) {         // Q/K parts
            const int part = col >> 12;
            const int h    = (col >> 9) & 7;
            const int e    = col & 511;
            dst = ((size_t)(part * 8 + h) * 8192 + row) * 512 + e;
            dstp = (u16*)Cv;
        } else {                       // EPI 6: O scatter
            const int zz = bz + z0;
            const int bb = zz & 15;
            const int hh = zz >> 4;
            dst = ((size_t)(bb * 512 + row)) * 4096 + hh * 512 + col;
            dstp = (u16*)Cv;
        }
        *(u16x8*)&dstp[dst] = w;
    }
}

// ---------- small kernels ----------

// fp32 [R,C] -> bf16 [C,R]
__global__ __launch_bounds__(256)
void transpose_cast(const float* __restrict__ in, u16* __restrict__ out, int R, int C) {
    __shared__ float t[32][33];
    const int tx = threadIdx.x & 31, ty = threadIdx.x >> 5;
    const int c0 = blockIdx.x * 32, r0 = blockIdx.y * 32;
#pragma unroll
    for (int j = 0; j < 4; ++j)
        t[ty + 8 * j][tx] = in[(size_t)(r0 + ty + 8 * j) * C + c0 + tx];
    __syncthreads();
#pragma unroll
    for (int j = 0; j < 4; ++j)
        out[(size_t)(c0 + ty + 8 * j) * R + r0 + tx] = f2bf(t[tx][ty + 8 * j]);
}

// three [512,4096] f32 -> bf16 [4096,512] transposes in one dispatch (z selects)
__global__ __launch_bounds__(256)
void transpose_cast3(const float* __restrict__ a, const float* __restrict__ b,
                     const float* __restrict__ c, u16* __restrict__ out) {
    const float* in = blockIdx.z == 0 ? a : (blockIdx.z == 1 ? b : c);
    u16* o = out + (size_t)blockIdx.z * 2097152;
    __shared__ float t[32][33];
    const int tx = threadIdx.x & 31, ty = threadIdx.x >> 5;
    const int c0 = blockIdx.x * 32, r0 = blockIdx.y * 32;
#pragma unroll
    for (int j = 0; j < 4; ++j)
        t[ty + 8 * j][tx] = in[(size_t)(r0 + ty + 8 * j) * 4096 + c0 + tx];
    __syncthreads();
#pragma unroll
    for (int j = 0; j < 4; ++j)
        o[(size_t)(c0 + ty + 8 * j) * 512 + r0 + tx] = f2bf(t[tx][ty + 8 * j]);
}

__global__ __launch_bounds__(256)
void pe_fill(float* __restrict__ pe) {
    const int idx = blockIdx.x * 256 + threadIdx.x;   // 512 pos x 256 freq-pairs
    const int p = idx >> 8, i2 = idx & 255;
    const float div = expf((float)(2 * i2) * -0.017988946039015984f);  // -ln(10000)/512
    const float arg = (float)p * div;
    pe[(p << 9) + 2 * i2]     = sinf(arg);
    pe[(p << 9) + 2 * i2 + 1] = cosf(arg);
}

__global__ __launch_bounds__(256)
void diag_fill(float* __restrict__ out, int n, float val) {
    const int i = blockIdx.x * 256 + threadIdx.x;
    if (i < n) out[i] = val;
}

// in-place row softmax of lambda*S, bf16; 4 rows per 256-thread block
__global__ __launch_bounds__(256)
void softmax_bf16(u16* __restrict__ S1, u16* __restrict__ S2, int n1) {
    const size_t row = (size_t)blockIdx.x * 4 + (threadIdx.x >> 6);
    const int lane = threadIdx.x & 63;
    u16* p = (row < (size_t)n1 ? S1 + (row << 9) : S2 + ((row - n1) << 9))
           + lane * 8;
    u16x8 w = *(u16x8*)p;
    float v[8];
#pragma unroll
    for (int j = 0; j < 8; ++j) v[j] = bf2f(w[j]);
    float m = fmaxf(fmaxf(fmaxf(v[0], v[1]), fmaxf(v[2], v[3])),
                    fmaxf(fmaxf(v[4], v[5]), fmaxf(v[6], v[7])));
#pragma unroll
    for (int o = 32; o > 0; o >>= 1) m = fmaxf(m, __shfl_xor(m, o, 64));
    const float lam = 0.044194173824159216f;   // 512^-0.5
    float s = 0.f;
#pragma unroll
    for (int j = 0; j < 8; ++j) { v[j] = __expf((v[j] - m) * lam); s += v[j]; }
#pragma unroll
    for (int o = 32; o > 0; o >>= 1) s += __shfl_xor(s, o, 64);
    const float inv = 1.0f / s;
#pragma unroll
    for (int j = 0; j < 8; ++j) w[j] = f2bf(v[j] * inv);
    *(u16x8*)p = w;
}

// split-K combine + bias + pooling-score dot, one block per token row
__global__ __launch_bounds__(256)
void combine_dot(const float* __restrict__ pk, const float* __restrict__ bu,
                 const float* __restrict__ qry, float* __restrict__ outb,
                 float* __restrict__ sc) {
    const int row = blockIdx.x, t = threadIdx.x;
    const size_t b0 = (size_t)row * 512;
    float o0 = pk[b0 + t]       + pk[b0 + t + 4194304]       + bu[t];
    float o1 = pk[b0 + t + 256] + pk[b0 + t + 256 + 4194304] + bu[t + 256];
    outb[b0 + t]       = o0;
    outb[b0 + t + 256] = o1;
    float acc = o0 * qry[t] + o1 * qry[t + 256];
    const int lane = t & 63, wid = t >> 6;
    __shared__ float red[4];
#pragma unroll
    for (int o = 32; o > 0; o >>= 1) acc += __shfl_xor(acc, o, 64);
    if (lane == 0) red[wid] = acc;
    __syncthreads();
    if (t == 0) sc[row] = red[0] + red[1] + red[2] + red[3];
}

__global__ __launch_bounds__(256)
void pool_softmax(const float* __restrict__ sc, float* __restrict__ p) {
    const int b = blockIdx.x, tid = threadIdx.x;
    const int lane = tid & 63, wid = tid >> 6;
    __shared__ float red[8];
    float v0 = sc[(b << 9) + tid];
    float v1 = sc[(b << 9) + 256 + tid];
    float m = fmaxf(v0, v1);
#pragma unroll
    for (int o = 32; o > 0; o >>= 1) m = fmaxf(m, __shfl_xor(m, o, 64));
    if (lane == 0) red[wid] = m;
    __syncthreads();
    m = fmaxf(fmaxf(red[0], red[1]), fmaxf(red[2], red[3]));
    float e0 = __expf(v0 - m), e1 = __expf(v1 - m);
    float s = e0 + e1;
#pragma unroll
    for (int o = 32; o > 0; o >>= 1) s += __shfl_xor(s, o, 64);
    if (lane == 0) red[4 + wid] = s;
    __syncthreads();
    s = red[4] + red[5] + red[6] + red[7];
    const float inv = 1.0f / s;
    p[(b << 9) + tid]       = e0 * inv;
    p[(b << 9) + 256 + tid] = e1 * inv;
}

// partial pooled sums over t-slices of 64
__global__ __launch_bounds__(512)
void pool_partial(const float* __restrict__ outb, const float* __restrict__ p,
                  float* __restrict__ part) {
    const int ts = blockIdx.x, b = blockIdx.y, e = threadIdx.x;
    float acc = 0.f;
#pragma unroll 8
    for (int tt = 0; tt < 64; ++tt) {
        const int t = ts * 64 + tt;
        acc += p[(b << 9) + t] * outb[((size_t)(b * 512 + t) << 9) + e];
    }
    part[((size_t)(ts * 16 + b) << 9) + e] = acc;
}

__global__ __launch_bounds__(256)
void pool_reduce(const float* __restrict__ part, float* __restrict__ dout) {
    const int i = blockIdx.x * 256 + threadIdx.x;  // 8192
    const int b = i >> 9, e = i & 511;
    float acc = 0.f;
#pragma unroll
    for (int ts = 0; ts < 8; ++ts) acc += part[((size_t)(ts * 16 + b) << 9) + e];
    dout[i] = acc;
}

// ---------- launch ----------

extern "C" void kernel_launch(void* const* d_in, const int* in_sizes, int n_in,
                              void* d_out, int out_size, void* d_ws, size_t ws_size,
                              hipStream_t stream)
{
    (void)in_sizes; (void)n_in;
    const float* x   = (const float*)d_in[0];
    const float* Wp  = (const float*)d_in[1];
    const float* Wk  = (const float*)d_in[2];   // dict order: W_k BEFORE W_q!
    const float* Wq  = (const float*)d_in[3];
    const float* Wv  = (const float*)d_in[4];
    const float* Wu  = (const float*)d_in[5];
    const float* bu  = (const float*)d_in[6];
    const float* qry = (const float*)d_in[7];

    char* ws = (char*)d_ws;
    const size_t NEED = 268435456ull;   // exactly 256 MiB (observed budget)
    if (ws_size < NEED) {
        diag_fill<<<(out_size + 255) / 256, 256, 0, stream>>>(
            (float*)d_out, out_size, (float)(ws_size >> 20));
        return;
    }

    // ---- byte-offset layout (lifetime-overlaid; R4/R7-proven) ----
    u16*   WpT   = (u16*)(ws + 0);            // [512,512]          dead after Xp
    u16*   WqT   = (u16*)(ws + 524288);       // [12288,512] concat dead after QKV
    float* peb   = (float*)(ws + 13107200);   // [512,512] f32      dead after Xp
    u16*   Xp    = (u16*)(ws + 14155776);     // [8192,512]         dead after QKV
    u16*   QKV   = (u16*)(ws + 22544384);     // Q|K|V(T), 192 MiB
    u16*   Qb    = QKV;                       // [8][16][512,512]   dead after S
    u16*   Kb    = (u16*)(ws + 89653248);     //                    dead after S
    u16*   Vt    = (u16*)(ws + 156762112);    // VT [h*16+b][e][t] (QKV epilogue)
    u16*   S1    = (u16*)(ws + 0);            // 43 chunks [512,512] bf16
    u16*   S2    = (u16*)(ws + 223870976);    // 85 chunks (tail)
    u16*   Ob    = (u16*)(ws + 22544384);     // [8192,4096] bf16 (over Q+, exact)
    float* partK = (float*)(ws + 89653248);   // [2][8192,512] f32 (over K)
    float* outb  = (float*)(ws + 123207680);  // [8192,512] f32
    u16*   WuT   = (u16*)(ws + 0);            // [512,4096] (after PV; over S1)
    float* scb   = (float*)(ws + 22544384);   // [8192]      (after unify; over Ob)
    float* poolp = (float*)(ws + 22577152);   // [128][512]
    float* pbf   = (float*)(ws + 22839296);   // [16][512]

    // setup
    transpose_cast<<<dim3(16, 16), 256, 0, stream>>>(Wp, WpT, 512, 512);
    transpose_cast3<<<dim3(128, 16, 3), 256, 0, stream>>>(Wq, Wk, Wv, WqT);
    pe_fill<<<512, 256, 0, stream>>>(peb);

    // Xp = bf16(x) @ WpT^T + pe     (f32 A, reg-staged cast)
    gemm_bt<0, 1, true><<<dim3(64, 4, 1), 256, 0, stream>>>(
        x, WpT, Xp, peb, 512, 512, 512, 0, 0, 0, nullptr, nullptr, 0);
    // QKV fused: [8192,512] @ [12288,512]^T; Q/K scattered, V written transposed
    gemm_bt<5, 2><<<dim3(64, 96, 1), 256, 0, stream>>>(
        Xp, WqT, QKV, nullptr, 512, 512, 512, 0, 0, 0, nullptr, nullptr, 0);

    // S = Q @ K^T (bf16, one z=128 dispatch; C base switch at z=43)
    gemm_bt<3, 0, false, 1><<<dim3(4, 4, 128), 256, 0, stream>>>(
        Qb, Kb, S1, nullptr, 512, 512, 512, 262144, 262144, 0, nullptr, S2, 43);

    // P = softmax(lambda*S) in place (one dispatch, 4 rows/block)
    softmax_bf16<<<16384, 256, 0, stream>>>(S1, S2, 22016);

    // O[b*t, h*512+e] = P @ V  (one z=128 dispatch; A base switch at z=43)
    gemm_bt<6, 0, false, 2><<<dim3(4, 4, 128), 256, 0, stream>>>(
        S1, Vt, Ob, nullptr, 512, 512, 512, 262144, 262144, 0, S2, nullptr, 43);

    // WuT cast now (S1 region dead after PV)
    transpose_cast<<<dim3(16, 128), 256, 0, stream>>>(Wu, WuT, 4096, 512);

    // out = O @ Wu + bu : split-K=2 partials, then fused combine+bias+dot
    gemm_bt<7, 1><<<dim3(64, 4, 2), 256, 0, stream>>>(
        Ob, WuT, partK, nullptr, 4096, 4096, 2048, 2048, 2048, 0, nullptr, nullptr, 0);
    combine_dot<<<8192, 256, 0, stream>>>(partK, bu, qry, outb, scb);

    // attention pooling
    pool_softmax<<<16, 256, 0, stream>>>(scb, pbf);
    pool_partial<<<dim3(8, 16), 512, 0, stream>>>(outb, pbf, poolp);
    pool_reduce<<<32, 256, 0, stream>>>(poolp, (float*)d_out);
}

// Round 12
// 416.478 us; speedup vs baseline: 1.0057x; 1.0057x over previous
//
#include <hip/hip_runtime.h>
#include <hip/hip_bf16.h>

typedef unsigned short u16;
typedef u16   u16x4  __attribute__((ext_vector_type(4)));
typedef u16   u16x8  __attribute__((ext_vector_type(8)));
typedef float f32x16 __attribute__((ext_vector_type(16)));

// ---------- helpers ----------

__device__ __forceinline__ u16 f2bf(float f) {
    union { float f; unsigned u; } v; v.f = f;
    unsigned u = v.u;
    unsigned r = (u + 0x7fffu + ((u >> 16) & 1u)) >> 16;   // RNE
    return (u16)r;
}
__device__ __forceinline__ float bf2f(u16 u) {
    union { unsigned u; float f; } x; x.u = (unsigned)u << 16; return x.f;
}

// 32x32x16 MFMA (inline asm). A/B: 4 VGPRs = 8 bf16; C/D: 16 f32.
__device__ __forceinline__ void mfma32(f32x16& d, u16x8 a, u16x8 b) {
    asm("v_mfma_f32_32x32x16_bf16 %0, %1, %2, %0" : "+v"(d) : "v"(a), "v"(b));
}

// ---------- unified GEMM: C = A[M,K] * (BT[N,K])^T, bf16 (or f32) in, f32 acc --
// Tile 128x128, BK=64, 256 threads = 4 waves (2x2 of 64x64), 32x32x16 MFMA
// (R10-proven: MfmaUtil 35%, conflicts 3.1e6, 790 TF).
// R11: T14 async-STAGE split — next tile's global loads issued AFTER barrier,
// BEFORE the MFMA cluster; vmcnt drain lands at next iteration's ds_write, so
// HBM latency hides under MFMA (m249: +3%; our stall frac larger).
// NOTE (R6/R8/R10 analysis): global_load_lds LDS image follows the address-
// ordered set, NOT lane order — per-lane source permutation within a coalesced
// set is a no-op; and per-row k-rotation is algebraically illegal for MFMA.
// gload_lds swizzle is closed. Reg-staged LDK=72 is the proven path.
// EPI: 0 = +pe(aux by row&511), bf16 out [.,512]           (staged)
//      3 = bf16 out batched: (bzc<<18) + row*512+col       (staged)
//      5 = QKV scatter by col; V-part written TRANSPOSED   (staged)
//      6 = O scatter: zz=bz+z0 -> (b,h); [8192,4096]       (staged)
//      7 = f32 split-K partial: Cv + (bz<<22) + row*512+col (direct)
// SWZ: 1 = bijective flat XCD remap; 2 = 8x8 supertile-per-XCD (QKV)
// AF32: A operand is f32, cast during staging (no prefetch; Xp only)
// SPLITZ: 1 = C base switch at z1 (EPI3); 2 = A base switch at z1 (EPI6)

#define LDK 72

template<int EPI, int SWZ = 0, bool AF32 = false, int SPLITZ = 0>
__global__ __launch_bounds__(256)
void gemm_bt(const void* __restrict__ Av, const u16* __restrict__ BT,
             void* __restrict__ Cv, const float* __restrict__ aux,
             int lda, int ldb, int K, long sAb, long sBb, int z0,
             const void* __restrict__ Av2, void* __restrict__ Cv2, int z1)
{
    __shared__ u16 smem[2][128 * LDK];   // 36864 B; epilogue cs reuses first 16384 elems
    u16* As = smem[0];
    u16* Bs = smem[1];

    const int tid  = threadIdx.x;
    const int lane = tid & 63;
    const int wid  = tid >> 6;
    const int wm   = wid >> 1, wn = wid & 1;
    const int bz   = blockIdx.z;

    int bx = blockIdx.x, by = blockIdx.y;
    if (SWZ == 1) {
        const int gx = gridDim.x;
        const int n  = gx * gridDim.y;      // must be %8==0
        const int q  = n >> 3;
        int f = by * gx + bx;
        f = (f & 7) * q + (f >> 3);
        bx = f % gx; by = f / gx;
    } else if (SWZ == 2) {                  // 8x8 supertiles, one per XCD
        const int orig = by * gridDim.x + bx;
        const int xcd  = orig & 7;
        const int j    = orig >> 3;
        const int s    = xcd + ((j >> 6) << 3);
        const int t    = j & 63;
        bx = ((s & 7) << 3) + (t & 7);
        by = ((s >> 3) << 3) + (t >> 3);
    }
    const int m0 = bx * 128;
    const int n0 = by * 128;

    const u16* Ab;
    const float* Af = (const float*)Av + (size_t)bz * sAb;
    if (SPLITZ == 2 && bz >= z1)
        Ab = (const u16*)Av2 + (size_t)(bz - z1) * sAb;
    else
        Ab = (const u16*)Av + (size_t)bz * sAb;
    const u16* Bb = BT + (size_t)bz * sBb;

    // C base switch (EPI 3)
    u16* Cb = (u16*)Cv;
    int bzc = bz;
    if (SPLITZ == 1 && bz >= z1) { Cb = (u16*)Cv2; bzc = bz - z1; }

    const int tr = tid >> 3;          // 0..31
    const int tc = (tid & 7) << 3;    // 0..56

    f32x16 acc[2][2];
#pragma unroll
    for (int i = 0; i < 2; ++i)
#pragma unroll
        for (int j = 0; j < 2; ++j)
            acc[i][j] = (f32x16){0.f,0.f,0.f,0.f,0.f,0.f,0.f,0.f,
                                 0.f,0.f,0.f,0.f,0.f,0.f,0.f,0.f};

    // VALU-write -> MFMA-srcC hazard fence
    asm volatile("s_nop 3"
        : "+v"(acc[0][0]), "+v"(acc[0][1]), "+v"(acc[1][0]), "+v"(acc[1][1]));

    const int fr = lane & 31;             // A/B operand row within 32-block
    const int q8 = (lane >> 5) << 3;      // k sub-chunk: 0 or 8

    // T14 prefetch registers (reg path only)
    u16x8 apre[4], bpre[4];
    auto ldtile = [&](int kt) {
#pragma unroll
        for (int j = 0; j < 4; ++j) {
            const int r = tr + 32 * j;
            apre[j] = *(const u16x8*)&Ab[(size_t)(m0 + r) * lda + kt + tc];
            bpre[j] = *(const u16x8*)&Bb[(size_t)(n0 + r) * ldb + kt + tc];
        }
    };
    if (!AF32) ldtile(0);

    for (int kt = 0; kt < K; kt += 64) {
        __syncthreads();
        if (AF32) {
#pragma unroll
            for (int j = 0; j < 4; ++j) {
                const int r = tr + 32 * j;
                const float* pa = &Af[(size_t)(m0 + r) * lda + kt + tc];
                float4 f0 = *(const float4*)pa;
                float4 f1 = *(const float4*)(pa + 4);
                u16x8 w = { f2bf(f0.x), f2bf(f0.y), f2bf(f0.z), f2bf(f0.w),
                            f2bf(f1.x), f2bf(f1.y), f2bf(f1.z), f2bf(f1.w) };
                *(u16x8*)&As[r * LDK + tc] = w;
                *(u16x8*)&Bs[r * LDK + tc] = *(const u16x8*)&Bb[(size_t)(n0 + r) * ldb + kt + tc];
            }
        } else {
#pragma unroll
            for (int j = 0; j < 4; ++j) {
                const int r = tr + 32 * j;
                *(u16x8*)&As[r * LDK + tc] = apre[j];
                *(u16x8*)&Bs[r * LDK + tc] = bpre[j];
            }
        }
        __syncthreads();
        if (!AF32 && kt + 64 < K) ldtile(kt + 64);   // issue-early; drained at next ds_write

#pragma unroll
        for (int ks = 0; ks < 4; ++ks) {
            const int ko = ks * 16 + q8;
            u16x8 a0 = *(const u16x8*)&As[(wm * 64 +      fr) * LDK + ko];
            u16x8 a1 = *(const u16x8*)&As[(wm * 64 + 32 + fr) * LDK + ko];
            u16x8 b0 = *(const u16x8*)&Bs[(wn * 64 +      fr) * LDK + ko];
            u16x8 b1 = *(const u16x8*)&Bs[(wn * 64 + 32 + fr) * LDK + ko];
            mfma32(acc[0][0], a0, b0);
            mfma32(acc[0][1], a0, b1);
            mfma32(acc[1][0], a1, b0);
            mfma32(acc[1][1], a1, b1);
        }
    }

    // MFMA-write -> VALU/VMEM-read hazard fence
    asm volatile("s_nop 7\n\ts_nop 7\n\ts_nop 7"
        : "+v"(acc[0][0]), "+v"(acc[0][1]), "+v"(acc[1][0]), "+v"(acc[1][1]));

    // C/D map (m74/m101): col = lane&31, row = (reg&3) + 8*(reg>>2) + 4*(lane>>5)
    const int lc = lane & 31;
    const int lq = (lane >> 5) << 2;

    if (EPI == 7) {   // direct f32 split-K partial
#pragma unroll
        for (int mi = 0; mi < 2; ++mi)
#pragma unroll
            for (int ni = 0; ni < 2; ++ni)
#pragma unroll
                for (int i = 0; i < 16; ++i) {
                    const int row = m0 + wm * 64 + mi * 32 + (i & 3) + 8 * (i >> 2) + lq;
                    const int col = n0 + wn * 64 + ni * 32 + lc;
                    ((float*)Cv)[((size_t)bz << 22) + (size_t)row * 512 + col] = acc[mi][ni][i];
                }
        return;
    }

    // staged bf16 epilogue via cs[128][128] (XOR-swizzled; R4-proven)
    u16* cs = (u16*)smem;
    auto cswz = [](int r, int c) { return r * 128 + (c ^ (((r >> 3) & 7) << 4)); };
    __syncthreads();
#pragma unroll
    for (int mi = 0; mi < 2; ++mi)
#pragma unroll
        for (int ni = 0; ni < 2; ++ni)
#pragma unroll
            for (int i = 0; i < 16; ++i) {
                const int rl = wm * 64 + mi * 32 + (i & 3) + 8 * (i >> 2) + lq;
                const int cl = wn * 64 + ni * 32 + lc;
                float v = acc[mi][ni][i];
                if (EPI == 0) v += aux[(((m0 + rl) & 511) << 9) + n0 + cl];
                cs[cswz(rl, cl)] = f2bf(v);
            }
    __syncthreads();

    if (EPI == 5 && n0 >= 8192) {
        // V part: write transposed -> VT[h*16+b][e][t]
        const int elq = tid >> 4;          // 0..15
        const int t8  = (tid & 15) << 3;   // 0..120
        const int hh  = (n0 >> 9) & 7;
        const int bb  = m0 >> 9;
        const int e0v = n0 & 511;
        const int t0v = m0 & 511;
        u16* Vbase = (u16*)Cv + 67108864;  // part-2 offset (elements)
#pragma unroll
        for (int q = 0; q < 8; ++q) {
            const int e_loc = q * 16 + elq;
            u16x8 w;
#pragma unroll
            for (int k = 0; k < 8; ++k) w[k] = cs[cswz(t8 + k, e_loc)];
            const size_t dst = ((size_t)(hh * 16 + bb) << 18)
                             + (size_t)(e0v + e_loc) * 512 + t0v + t8;
            *(u16x8*)&Vbase[dst] = w;
        }
        return;
    }

    const int frl = tid >> 4;          // 0..15
    const int fc8 = (tid & 15) << 3;   // 0..120
#pragma unroll
    for (int p = 0; p < 8; ++p) {
        const int rl = p * 16 + frl;
        u16x8 w = *(u16x8*)&cs[rl * 128 + (fc8 ^ (((rl >> 3) & 7) << 4))];
        const int row = m0 + rl;
        const int col = n0 + fc8;
        size_t dst;
        u16* dstp;
        if (EPI == 0) {
            dst = (size_t)row * 512 + col;
            dstp = (u16*)Cv;
        } else if (EPI == 3) {
            dst = ((size_t)bzc << 18) + ((size_t)row << 9) + col;
            dstp = Cb;
        } else if (EPI == 5) {         // Q/K parts
            const int part = col >> 12;
            const int h    = (col >> 9) & 7;
            const int e    = col & 511;
            dst = ((size_t)(part * 8 + h) * 8192 + row) * 512 + e;
            dstp = (u16*)Cv;
        } else {                       // EPI 6: O scatter
            const int zz = bz + z0;
            const int bb = zz & 15;
            const int hh = zz >> 4;
            dst = ((size_t)(bb * 512 + row)) * 4096 + hh * 512 + col;
            dstp = (u16*)Cv;
        }
        *(u16x8*)&dstp[dst] = w;
    }
}

// ---------- small kernels ----------

// fp32 [R,C] -> bf16 [C,R]
__global__ __launch_bounds__(256)
void transpose_cast(const float* __restrict__ in, u16* __restrict__ out, int R, int C) {
    __shared__ float t[32][33];
    const int tx = threadIdx.x & 31, ty = threadIdx.x >> 5;
    const int c0 = blockIdx.x * 32, r0 = blockIdx.y * 32;
#pragma unroll
    for (int j = 0; j < 4; ++j)
        t[ty + 8 * j][tx] = in[(size_t)(r0 + ty + 8 * j) * C + c0 + tx];
    __syncthreads();
#pragma unroll
    for (int j = 0; j < 4; ++j)
        out[(size_t)(c0 + ty + 8 * j) * R + r0 + tx] = f2bf(t[tx][ty + 8 * j]);
}

// three [512,4096] f32 -> bf16 [4096,512] transposes in one dispatch (z selects)
__global__ __launch_bounds__(256)
void transpose_cast3(const float* __restrict__ a, const float* __restrict__ b,
                     const float* __restrict__ c, u16* __restrict__ out) {
    const float* in = blockIdx.z == 0 ? a : (blockIdx.z == 1 ? b : c);
    u16* o = out + (size_t)blockIdx.z * 2097152;
    __shared__ float t[32][33];
    const int tx = threadIdx.x & 31, ty = threadIdx.x >> 5;
    const int c0 = blockIdx.x * 32, r0 = blockIdx.y * 32;
#pragma unroll
    for (int j = 0; j < 4; ++j)
        t[ty + 8 * j][tx] = in[(size_t)(r0 + ty + 8 * j) * 4096 + c0 + tx];
    __syncthreads();
#pragma unroll
    for (int j = 0; j < 4; ++j)
        o[(size_t)(c0 + ty + 8 * j) * 512 + r0 + tx] = f2bf(t[tx][ty + 8 * j]);
}

__global__ __launch_bounds__(256)
void pe_fill(float* __restrict__ pe) {
    const int idx = blockIdx.x * 256 + threadIdx.x;   // 512 pos x 256 freq-pairs
    const int p = idx >> 8, i2 = idx & 255;
    const float div = expf((float)(2 * i2) * -0.017988946039015984f);  // -ln(10000)/512
    const float arg = (float)p * div;
    pe[(p << 9) + 2 * i2]     = sinf(arg);
    pe[(p << 9) + 2 * i2 + 1] = cosf(arg);
}

__global__ __launch_bounds__(256)
void diag_fill(float* __restrict__ out, int n, float val) {
    const int i = blockIdx.x * 256 + threadIdx.x;
    if (i < n) out[i] = val;
}

// in-place row softmax of lambda*S, bf16; 4 rows per 256-thread block
__global__ __launch_bounds__(256)
void softmax_bf16(u16* __restrict__ S1, u16* __restrict__ S2, int n1) {
    const size_t row = (size_t)blockIdx.x * 4 + (threadIdx.x >> 6);
    const int lane = threadIdx.x & 63;
    u16* p = (row < (size_t)n1 ? S1 + (row << 9) : S2 + ((row - n1) << 9))
           + lane * 8;
    u16x8 w = *(u16x8*)p;
    float v[8];
#pragma unroll
    for (int j = 0; j < 8; ++j) v[j] = bf2f(w[j]);
    float m = fmaxf(fmaxf(fmaxf(v[0], v[1]), fmaxf(v[2], v[3])),
                    fmaxf(fmaxf(v[4], v[5]), fmaxf(v[6], v[7])));
#pragma unroll
    for (int o = 32; o > 0; o >>= 1) m = fmaxf(m, __shfl_xor(m, o, 64));
    const float lam = 0.044194173824159216f;   // 512^-0.5
    float s = 0.f;
#pragma unroll
    for (int j = 0; j < 8; ++j) { v[j] = __expf((v[j] - m) * lam); s += v[j]; }
#pragma unroll
    for (int o = 32; o > 0; o >>= 1) s += __shfl_xor(s, o, 64);
    const float inv = 1.0f / s;
#pragma unroll
    for (int j = 0; j < 8; ++j) w[j] = f2bf(v[j] * inv);
    *(u16x8*)p = w;
}

// split-K combine + bias + pooling-score dot, one block per token row
__global__ __launch_bounds__(256)
void combine_dot(const float* __restrict__ pk, const float* __restrict__ bu,
                 const float* __restrict__ qry, float* __restrict__ outb,
                 float* __restrict__ sc) {
    const int row = blockIdx.x, t = threadIdx.x;
    const size_t b0 = (size_t)row * 512;
    float o0 = pk[b0 + t]       + pk[b0 + t + 4194304]       + bu[t];
    float o1 = pk[b0 + t + 256] + pk[b0 + t + 256 + 4194304] + bu[t + 256];
    outb[b0 + t]       = o0;
    outb[b0 + t + 256] = o1;
    float acc = o0 * qry[t] + o1 * qry[t + 256];
    const int lane = t & 63, wid = t >> 6;
    __shared__ float red[4];
#pragma unroll
    for (int o = 32; o > 0; o >>= 1) acc += __shfl_xor(acc, o, 64);
    if (lane == 0) red[wid] = acc;
    __syncthreads();
    if (t == 0) sc[row] = red[0] + red[1] + red[2] + red[3];
}

__global__ __launch_bounds__(256)
void pool_softmax(const float* __restrict__ sc, float* __restrict__ p) {
    const int b = blockIdx.x, tid = threadIdx.x;
    const int lane = tid & 63, wid = tid >> 6;
    __shared__ float red[8];
    float v0 = sc[(b << 9) + tid];
    float v1 = sc[(b << 9) + 256 + tid];
    float m = fmaxf(v0, v1);
#pragma unroll
    for (int o = 32; o > 0; o >>= 1) m = fmaxf(m, __shfl_xor(m, o, 64));
    if (lane == 0) red[wid] = m;
    __syncthreads();
    m = fmaxf(fmaxf(red[0], red[1]), fmaxf(red[2], red[3]));
    float e0 = __expf(v0 - m), e1 = __expf(v1 - m);
    float s = e0 + e1;
#pragma unroll
    for (int o = 32; o > 0; o >>= 1) s += __shfl_xor(s, o, 64);
    if (lane == 0) red[4 + wid] = s;
    __syncthreads();
    s = red[4] + red[5] + red[6] + red[7];
    const float inv = 1.0f / s;
    p[(b << 9) + tid]       = e0 * inv;
    p[(b << 9) + 256 + tid] = e1 * inv;
}

// partial pooled sums over t-slices of 64
__global__ __launch_bounds__(512)
void pool_partial(const float* __restrict__ outb, const float* __restrict__ p,
                  float* __restrict__ part) {
    const int ts = blockIdx.x, b = blockIdx.y, e = threadIdx.x;
    float acc = 0.f;
#pragma unroll 8
    for (int tt = 0; tt < 64; ++tt) {
        const int t = ts * 64 + tt;
        acc += p[(b << 9) + t] * outb[((size_t)(b * 512 + t) << 9) + e];
    }
    part[((size_t)(ts * 16 + b) << 9) + e] = acc;
}

__global__ __launch_bounds__(256)
void pool_reduce(const float* __restrict__ part, float* __restrict__ dout) {
    const int i = blockIdx.x * 256 + threadIdx.x;  // 8192
    const int b = i >> 9, e = i & 511;
    float acc = 0.f;
#pragma unroll
    for (int ts = 0; ts < 8; ++ts) acc += part[((size_t)(ts * 16 + b) << 9) + e];
    dout[i] = acc;
}

// ---------- launch ----------

extern "C" void kernel_launch(void* const* d_in, const int* in_sizes, int n_in,
                              void* d_out, int out_size, void* d_ws, size_t ws_size,
                              hipStream_t stream)
{
    (void)in_sizes; (void)n_in;
    const float* x   = (const float*)d_in[0];
    const float* Wp  = (const float*)d_in[1];
    const float* Wk  = (const float*)d_in[2];   // dict order: W_k BEFORE W_q!
    const float* Wq  = (const float*)d_in[3];
    const float* Wv  = (const float*)d_in[4];
    const float* Wu  = (const float*)d_in[5];
    const float* bu  = (const float*)d_in[6];
    const float* qry = (const float*)d_in[7];

    char* ws = (char*)d_ws;
    const size_t NEED = 268435456ull;   // exactly 256 MiB (observed budget)
    if (ws_size < NEED) {
        diag_fill<<<(out_size + 255) / 256, 256, 0, stream>>>(
            (float*)d_out, out_size, (float)(ws_size >> 20));
        return;
    }

    // ---- byte-offset layout (lifetime-overlaid; R4/R7-proven) ----
    u16*   WpT   = (u16*)(ws + 0);            // [512,512]          dead after Xp
    u16*   WqT   = (u16*)(ws + 524288);       // [12288,512] concat dead after QKV
    float* peb   = (float*)(ws + 13107200);   // [512,512] f32      dead after Xp
    u16*   Xp    = (u16*)(ws + 14155776);     // [8192,512]         dead after QKV
    u16*   QKV   = (u16*)(ws + 22544384);     // Q|K|V(T), 192 MiB
    u16*   Qb    = QKV;                       // [8][16][512,512]   dead after S
    u16*   Kb    = (u16*)(ws + 89653248);     //                    dead after S
    u16*   Vt    = (u16*)(ws + 156762112);    // VT [h*16+b][e][t] (QKV epilogue)
    u16*   S1    = (u16*)(ws + 0);            // 43 chunks [512,512] bf16
    u16*   S2    = (u16*)(ws + 223870976);    // 85 chunks (tail)
    u16*   Ob    = (u16*)(ws + 22544384);     // [8192,4096] bf16 (over Q+, exact)
    float* partK = (float*)(ws + 89653248);   // [2][8192,512] f32 (over K)
    float* outb  = (float*)(ws + 123207680);  // [8192,512] f32
    u16*   WuT   = (u16*)(ws + 0);            // [512,4096] (after PV; over S1)
    float* scb   = (float*)(ws + 22544384);   // [8192]      (after unify; over Ob)
    float* poolp = (float*)(ws + 22577152);   // [128][512]
    float* pbf   = (float*)(ws + 22839296);   // [16][512]

    // setup
    transpose_cast<<<dim3(16, 16), 256, 0, stream>>>(Wp, WpT, 512, 512);
    transpose_cast3<<<dim3(128, 16, 3), 256, 0, stream>>>(Wq, Wk, Wv, WqT);
    pe_fill<<<512, 256, 0, stream>>>(peb);

    // Xp = bf16(x) @ WpT^T + pe     (f32 A, reg-staged cast)
    gemm_bt<0, 1, true><<<dim3(64, 4, 1), 256, 0, stream>>>(
        x, WpT, Xp, peb, 512, 512, 512, 0, 0, 0, nullptr, nullptr, 0);
    // QKV fused: [8192,512] @ [12288,512]^T; Q/K scattered, V written transposed
    gemm_bt<5, 2><<<dim3(64, 96, 1), 256, 0, stream>>>(
        Xp, WqT, QKV, nullptr, 512, 512, 512, 0, 0, 0, nullptr, nullptr, 0);

    // S = Q @ K^T (bf16, one z=128 dispatch; C base switch at z=43)
    gemm_bt<3, 0, false, 1><<<dim3(4, 4, 128), 256, 0, stream>>>(
        Qb, Kb, S1, nullptr, 512, 512, 512, 262144, 262144, 0, nullptr, S2, 43);

    // P = softmax(lambda*S) in place (one dispatch, 4 rows/block)
    softmax_bf16<<<16384, 256, 0, stream>>>(S1, S2, 22016);

    // O[b*t, h*512+e] = P @ V  (one z=128 dispatch; A base switch at z=43)
    gemm_bt<6, 0, false, 2><<<dim3(4, 4, 128), 256, 0, stream>>>(
        S1, Vt, Ob, nullptr, 512, 512, 512, 262144, 262144, 0, S2, nullptr, 43);

    // WuT cast now (S1 region dead after PV)
    transpose_cast<<<dim3(16, 128), 256, 0, stream>>>(Wu, WuT, 4096, 512);

    // out = O @ Wu + bu : split-K=2 partials, then fused combine+bias+dot
    gemm_bt<7, 1><<<dim3(64, 4, 2), 256, 0, stream>>>(
        Ob, WuT, partK, nullptr, 4096, 4096, 2048, 2048, 2048, 0, nullptr, nullptr, 0);
    combine_dot<<<8192, 256, 0, stream>>>(partK, bu, qry, outb, scb);

    // attention pooling
    pool_softmax<<<16, 256, 0, stream>>>(scb, pbf);
    pool_partial<<<dim3(8, 16), 512, 0, stream>>>(outb, pbf, poolp);
    pool_reduce<<<32, 256, 0, stream>>>(poolp, (float*)d_out);
}

// Round 13
// 375.596 us; speedup vs baseline: 1.1152x; 1.1088x over previous
//
#include <hip/hip_runtime.h>
#include <hip/hip_bf16.h>

typedef unsigned short u16;
typedef u16   u16x4  __attribute__((ext_vector_type(4)));
typedef u16   u16x8  __attribute__((ext_vector_type(8)));
typedef float f32x16 __attribute__((ext_vector_type(16)));

// ---------- helpers ----------

__device__ __forceinline__ u16 f2bf(float f) {
    union { float f; unsigned u; } v; v.f = f;
    unsigned u = v.u;
    unsigned r = (u + 0x7fffu + ((u >> 16) & 1u)) >> 16;   // RNE
    return (u16)r;
}
__device__ __forceinline__ float bf2f(u16 u) {
    union { unsigned u; float f; } x; x.u = (unsigned)u << 16; return x.f;
}

// 32x32x16 MFMA (inline asm). A/B: 4 VGPRs = 8 bf16; C/D: 16 f32.
__device__ __forceinline__ void mfma32(f32x16& d, u16x8 a, u16x8 b) {
    asm("v_mfma_f32_32x32x16_bf16 %0, %1, %2, %0" : "+v"(d) : "v"(a), "v"(b));
}

// ---------- unified GEMM: C = A[M,K] * (BT[N,K])^T, bf16 (or f32) in, f32 acc --
// Tile 128x128, BK=64, 256 threads = 4 waves (2x2 of 64x64), 32x32x16 MFMA
// (R10-proven: MfmaUtil 35%, conflicts 3.1e6, 790 TF, VGPR 64).
// R12 lesson: T14 reg-prefetch REVERTED (+12 VGPR -> occupancy 39->30%, net -7%).
// R13: algebraic restructure — S = Xp (WqWk^T) Xp^T; Q/K never materialized.
// NOTE (R6/R8/R10): global_load_lds LDS image follows the address-ordered set,
// not lane order — source-permutation swizzle is a no-op; gload path closed.
// EPI: 0 = +pe(aux by row&511), bf16 out [.,512]           (staged)
//      3 = bf16 out batched: (bz<<18) + row*512+col        (staged)
//      6 = O scatter: bz -> (b=bz>>3, h=bz&7); [8192,4096] (staged)
//      7 = f32 split-K partial: Cv + (bz<<22) + row*512+col (direct)
//      8 = V-transpose: Vt[(b*8+h)][e][t], b=m0>>9, h=n0>>9 (staged)
// SWZ: 1 = bijective flat XCD remap; 2 = 8x8 supertile-per-XCD
// AF32: A operand is f32, cast during staging
// ASEL: A batch index: 0 = bz, 1 = bz>>3
// BSEL: B batch index: 0 = bz, 1 = bz>>3, 2 = bz&7

#define LDK 72

template<int EPI, int SWZ = 0, bool AF32 = false, int ASEL = 0, int BSEL = 0>
__global__ __launch_bounds__(256)
void gemm_bt(const void* __restrict__ Av, const u16* __restrict__ BT,
             void* __restrict__ Cv, const float* __restrict__ aux,
             int lda, int ldb, int K, long sAb, long sBb)
{
    __shared__ u16 smem[2][128 * LDK];   // 36864 B; epilogue cs reuses first 16384 elems
    u16* As = smem[0];
    u16* Bs = smem[1];

    const int tid  = threadIdx.x;
    const int lane = tid & 63;
    const int wid  = tid >> 6;
    const int wm   = wid >> 1, wn = wid & 1;
    const int bz   = blockIdx.z;

    int bx = blockIdx.x, by = blockIdx.y;
    if (SWZ == 1) {
        const int gx = gridDim.x;
        const int n  = gx * gridDim.y;      // must be %8==0
        const int q  = n >> 3;
        int f = by * gx + bx;
        f = (f & 7) * q + (f >> 3);
        bx = f % gx; by = f / gx;
    } else if (SWZ == 2) {                  // 8x8 supertiles, one per XCD
        const int orig = by * gridDim.x + bx;
        const int xcd  = orig & 7;
        const int j    = orig >> 3;
        const int s    = xcd + ((j >> 6) << 3);
        const int t    = j & 63;
        bx = ((s & 7) << 3) + (t & 7);
        by = ((s >> 3) << 3) + (t >> 3);
    }
    const int m0 = bx * 128;
    const int n0 = by * 128;

    const long az = (ASEL == 0) ? bz : (bz >> 3);
    const long bzb = (BSEL == 0) ? bz : (BSEL == 1 ? (bz >> 3) : (bz & 7));
    const u16*   Ab = (const u16*)Av   + az * sAb;
    const float* Af = (const float*)Av + az * sAb;
    const u16*   Bb = BT + bzb * sBb;

    const int tr = tid >> 3;          // 0..31
    const int tc = (tid & 7) << 3;    // 0..56

    f32x16 acc[2][2];
#pragma unroll
    for (int i = 0; i < 2; ++i)
#pragma unroll
        for (int j = 0; j < 2; ++j)
            acc[i][j] = (f32x16){0.f,0.f,0.f,0.f,0.f,0.f,0.f,0.f,
                                 0.f,0.f,0.f,0.f,0.f,0.f,0.f,0.f};

    // VALU-write -> MFMA-srcC hazard fence
    asm volatile("s_nop 3"
        : "+v"(acc[0][0]), "+v"(acc[0][1]), "+v"(acc[1][0]), "+v"(acc[1][1]));

    const int fr = lane & 31;             // A/B operand row within 32-block
    const int q8 = (lane >> 5) << 3;      // k sub-chunk: 0 or 8

    for (int kt = 0; kt < K; kt += 64) {
        __syncthreads();
#pragma unroll
        for (int j = 0; j < 4; ++j) {
            const int r = tr + 32 * j;
            if (AF32) {
                const float* pa = &Af[(size_t)(m0 + r) * lda + kt + tc];
                float4 f0 = *(const float4*)pa;
                float4 f1 = *(const float4*)(pa + 4);
                u16x8 w = { f2bf(f0.x), f2bf(f0.y), f2bf(f0.z), f2bf(f0.w),
                            f2bf(f1.x), f2bf(f1.y), f2bf(f1.z), f2bf(f1.w) };
                *(u16x8*)&As[r * LDK + tc] = w;
            } else {
                *(u16x8*)&As[r * LDK + tc] = *(const u16x8*)&Ab[(size_t)(m0 + r) * lda + kt + tc];
            }
            *(u16x8*)&Bs[r * LDK + tc] = *(const u16x8*)&Bb[(size_t)(n0 + r) * ldb + kt + tc];
        }
        __syncthreads();

#pragma unroll
        for (int ks = 0; ks < 4; ++ks) {
            const int ko = ks * 16 + q8;
            u16x8 a0 = *(const u16x8*)&As[(wm * 64 +      fr) * LDK + ko];
            u16x8 a1 = *(const u16x8*)&As[(wm * 64 + 32 + fr) * LDK + ko];
            u16x8 b0 = *(const u16x8*)&Bs[(wn * 64 +      fr) * LDK + ko];
            u16x8 b1 = *(const u16x8*)&Bs[(wn * 64 + 32 + fr) * LDK + ko];
            mfma32(acc[0][0], a0, b0);
            mfma32(acc[0][1], a0, b1);
            mfma32(acc[1][0], a1, b0);
            mfma32(acc[1][1], a1, b1);
        }
    }

    // MFMA-write -> VALU/VMEM-read hazard fence
    asm volatile("s_nop 7\n\ts_nop 7\n\ts_nop 7"
        : "+v"(acc[0][0]), "+v"(acc[0][1]), "+v"(acc[1][0]), "+v"(acc[1][1]));

    // C/D map (m74/m101): col = lane&31, row = (reg&3) + 8*(reg>>2) + 4*(lane>>5)
    const int lc = lane & 31;
    const int lq = (lane >> 5) << 2;

    if (EPI == 7) {   // direct f32 split-K partial
#pragma unroll
        for (int mi = 0; mi < 2; ++mi)
#pragma unroll
            for (int ni = 0; ni < 2; ++ni)
#pragma unroll
                for (int i = 0; i < 16; ++i) {
                    const int row = m0 + wm * 64 + mi * 32 + (i & 3) + 8 * (i >> 2) + lq;
                    const int col = n0 + wn * 64 + ni * 32 + lc;
                    ((float*)Cv)[((size_t)bz << 22) + (size_t)row * 512 + col] = acc[mi][ni][i];
                }
        return;
    }

    // staged bf16 epilogue via cs[128][128] (XOR-swizzled; R4-proven)
    u16* cs = (u16*)smem;
    auto cswz = [](int r, int c) { return r * 128 + (c ^ (((r >> 3) & 7) << 4)); };
    __syncthreads();
#pragma unroll
    for (int mi = 0; mi < 2; ++mi)
#pragma unroll
        for (int ni = 0; ni < 2; ++ni)
#pragma unroll
            for (int i = 0; i < 16; ++i) {
                const int rl = wm * 64 + mi * 32 + (i & 3) + 8 * (i >> 2) + lq;
                const int cl = wn * 64 + ni * 32 + lc;
                float v = acc[mi][ni][i];
                if (EPI == 0) v += aux[(((m0 + rl) & 511) << 9) + n0 + cl];
                cs[cswz(rl, cl)] = f2bf(v);
            }
    __syncthreads();

    if (EPI == 8) {
        // V written transposed -> Vt[(b*8+h)][e][t]
        const int elq = tid >> 4;          // 0..15
        const int t8  = (tid & 15) << 3;   // 0..120
        const int hh  = n0 >> 9;
        const int bb  = m0 >> 9;
        const int e0v = n0 & 511;
        const int t0v = m0 & 511;
#pragma unroll
        for (int q = 0; q < 8; ++q) {
            const int e_loc = q * 16 + elq;
            u16x8 w;
#pragma unroll
            for (int k = 0; k < 8; ++k) w[k] = cs[cswz(t8 + k, e_loc)];
            const size_t dst = ((size_t)(bb * 8 + hh) << 18)
                             + (size_t)(e0v + e_loc) * 512 + t0v + t8;
            *(u16x8*)&((u16*)Cv)[dst] = w;
        }
        return;
    }

    const int frl = tid >> 4;          // 0..15
    const int fc8 = (tid & 15) << 3;   // 0..120
#pragma unroll
    for (int p = 0; p < 8; ++p) {
        const int rl = p * 16 + frl;
        u16x8 w = *(u16x8*)&cs[rl * 128 + (fc8 ^ (((rl >> 3) & 7) << 4))];
        const int row = m0 + rl;
        const int col = n0 + fc8;
        size_t dst;
        if (EPI == 0) {
            dst = (size_t)row * 512 + col;
        } else if (EPI == 3) {
            dst = ((size_t)bz << 18) + ((size_t)row << 9) + col;
        } else {                       // EPI 6: O scatter, bz -> (b,h)
            const int bb = bz >> 3;
            const int hh = bz & 7;
            dst = ((size_t)(bb * 512 + row)) * 4096 + hh * 512 + col;
        }
        *(u16x8*)&((u16*)Cv)[dst] = w;
    }
}

// ---------- small kernels ----------

// fp32 [R,C] -> bf16 [C,R]
__global__ __launch_bounds__(256)
void transpose_cast(const float* __restrict__ in, u16* __restrict__ out, int R, int C) {
    __shared__ float t[32][33];
    const int tx = threadIdx.x & 31, ty = threadIdx.x >> 5;
    const int c0 = blockIdx.x * 32, r0 = blockIdx.y * 32;
#pragma unroll
    for (int j = 0; j < 4; ++j)
        t[ty + 8 * j][tx] = in[(size_t)(r0 + ty + 8 * j) * C + c0 + tx];
    __syncthreads();
#pragma unroll
    for (int j = 0; j < 4; ++j)
        out[(size_t)(c0 + ty + 8 * j) * R + r0 + tx] = f2bf(t[tx][ty + 8 * j]);
}

// straight casts: z=0 Wq->WqC, z=1 Wk->WkC  ([512,4096] f32 -> bf16, same layout)
__global__ __launch_bounds__(256)
void cast2(const float* __restrict__ a, const float* __restrict__ b,
           u16* __restrict__ oa, u16* __restrict__ ob) {
    const float* in = blockIdx.z == 0 ? a : b;
    u16* o = blockIdx.z == 0 ? oa : ob;
    const int i = blockIdx.x * 256 + threadIdx.x;   // 524288 f32x4 groups
    float4 v = ((const float4*)in)[i];
    u16x4 w = { f2bf(v.x), f2bf(v.y), f2bf(v.z), f2bf(v.w) };
    ((u16x4*)o)[i] = w;
}

__global__ __launch_bounds__(256)
void pe_fill(float* __restrict__ pe) {
    const int idx = blockIdx.x * 256 + threadIdx.x;   // 512 pos x 256 freq-pairs
    const int p = idx >> 8, i2 = idx & 255;
    const float div = expf((float)(2 * i2) * -0.017988946039015984f);  // -ln(10000)/512
    const float arg = (float)p * div;
    pe[(p << 9) + 2 * i2]     = sinf(arg);
    pe[(p << 9) + 2 * i2 + 1] = cosf(arg);
}

__global__ __launch_bounds__(256)
void diag_fill(float* __restrict__ out, int n, float val) {
    const int i = blockIdx.x * 256 + threadIdx.x;
    if (i < n) out[i] = val;
}

// in-place row softmax of lambda*S, bf16; 4 rows per 256-thread block
__global__ __launch_bounds__(256)
void softmax_bf16(u16* __restrict__ S) {
    const size_t row = (size_t)blockIdx.x * 4 + (threadIdx.x >> 6);
    const int lane = threadIdx.x & 63;
    u16* p = S + (row << 9) + lane * 8;
    u16x8 w = *(u16x8*)p;
    float v[8];
#pragma unroll
    for (int j = 0; j < 8; ++j) v[j] = bf2f(w[j]);
    float m = fmaxf(fmaxf(fmaxf(v[0], v[1]), fmaxf(v[2], v[3])),
                    fmaxf(fmaxf(v[4], v[5]), fmaxf(v[6], v[7])));
#pragma unroll
    for (int o = 32; o > 0; o >>= 1) m = fmaxf(m, __shfl_xor(m, o, 64));
    const float lam = 0.044194173824159216f;   // 512^-0.5
    float s = 0.f;
#pragma unroll
    for (int j = 0; j < 8; ++j) { v[j] = __expf((v[j] - m) * lam); s += v[j]; }
#pragma unroll
    for (int o = 32; o > 0; o >>= 1) s += __shfl_xor(s, o, 64);
    const float inv = 1.0f / s;
#pragma unroll
    for (int j = 0; j < 8; ++j) w[j] = f2bf(v[j] * inv);
    *(u16x8*)p = w;
}

// split-K combine + bias + pooling-score dot, one block per token row
__global__ __launch_bounds__(256)
void combine_dot(const float* __restrict__ pk, const float* __restrict__ bu,
                 const float* __restrict__ qry, float* __restrict__ outb,
                 float* __restrict__ sc) {
    const int row = blockIdx.x, t = threadIdx.x;
    const size_t b0 = (size_t)row * 512;
    float o0 = pk[b0 + t]       + pk[b0 + t + 4194304]       + bu[t];
    float o1 = pk[b0 + t + 256] + pk[b0 + t + 256 + 4194304] + bu[t + 256];
    outb[b0 + t]       = o0;
    outb[b0 + t + 256] = o1;
    float acc = o0 * qry[t] + o1 * qry[t + 256];
    const int lane = t & 63, wid = t >> 6;
    __shared__ float red[4];
#pragma unroll
    for (int o = 32; o > 0; o >>= 1) acc += __shfl_xor(acc, o, 64);
    if (lane == 0) red[wid] = acc;
    __syncthreads();
    if (t == 0) sc[row] = red[0] + red[1] + red[2] + red[3];
}

__global__ __launch_bounds__(256)
void pool_softmax(const float* __restrict__ sc, float* __restrict__ p) {
    const int b = blockIdx.x, tid = threadIdx.x;
    const int lane = tid & 63, wid = tid >> 6;
    __shared__ float red[8];
    float v0 = sc[(b << 9) + tid];
    float v1 = sc[(b << 9) + 256 + tid];
    float m = fmaxf(v0, v1);
#pragma unroll
    for (int o = 32; o > 0; o >>= 1) m = fmaxf(m, __shfl_xor(m, o, 64));
    if (lane == 0) red[wid] = m;
    __syncthreads();
    m = fmaxf(fmaxf(red[0], red[1]), fmaxf(red[2], red[3]));
    float e0 = __expf(v0 - m), e1 = __expf(v1 - m);
    float s = e0 + e1;
#pragma unroll
    for (int o = 32; o > 0; o >>= 1) s += __shfl_xor(s, o, 64);
    if (lane == 0) red[4 + wid] = s;
    __syncthreads();
    s = red[4] + red[5] + red[6] + red[7];
    const float inv = 1.0f / s;
    p[(b << 9) + tid]       = e0 * inv;
    p[(b << 9) + 256 + tid] = e1 * inv;
}

// partial pooled sums over t-slices of 64
__global__ __launch_bounds__(512)
void pool_partial(const float* __restrict__ outb, const float* __restrict__ p,
                  float* __restrict__ part) {
    const int ts = blockIdx.x, b = blockIdx.y, e = threadIdx.x;
    float acc = 0.f;
#pragma unroll 8
    for (int tt = 0; tt < 64; ++tt) {
        const int t = ts * 64 + tt;
        acc += p[(b << 9) + t] * outb[((size_t)(b * 512 + t) << 9) + e];
    }
    part[((size_t)(ts * 16 + b) << 9) + e] = acc;
}

__global__ __launch_bounds__(256)
void pool_reduce(const float* __restrict__ part, float* __restrict__ dout) {
    const int i = blockIdx.x * 256 + threadIdx.x;  // 8192
    const int b = i >> 9, e = i & 511;
    float acc = 0.f;
#pragma unroll
    for (int ts = 0; ts < 8; ++ts) acc += part[((size_t)(ts * 16 + b) << 9) + e];
    dout[i] = acc;
}

// ---------- launch ----------

extern "C" void kernel_launch(void* const* d_in, const int* in_sizes, int n_in,
                              void* d_out, int out_size, void* d_ws, size_t ws_size,
                              hipStream_t stream)
{
    (void)in_sizes; (void)n_in;
    const float* x   = (const float*)d_in[0];
    const float* Wp  = (const float*)d_in[1];
    const float* Wk  = (const float*)d_in[2];   // dict order: W_k BEFORE W_q!
    const float* Wq  = (const float*)d_in[3];
    const float* Wv  = (const float*)d_in[4];
    const float* Wu  = (const float*)d_in[5];
    const float* bu  = (const float*)d_in[6];
    const float* qry = (const float*)d_in[7];

    char* ws = (char*)d_ws;
    const size_t NEED = 261619712ull;   // fits 256 MiB budget
    if (ws_size < NEED) {
        diag_fill<<<(out_size + 255) / 256, 256, 0, stream>>>(
            (float*)d_out, out_size, (float)(ws_size >> 20));
        return;
    }

    // ---- byte-offset layout (lifetime-overlaid) ----
    u16*   WpT   = (u16*)(ws + 0);            // [512,512]      dead after Xp
    u16*   WqC   = (u16*)(ws + 524288);       // [512,4096] bf16, straight cast
    u16*   WkC   = (u16*)(ws + 4718592);      // [512,4096] bf16
    u16*   Mbuf  = (u16*)(ws + 8912896);      // MT[h][512,512] bf16, 4 MiB
    float* peb   = (float*)(ws + 13107200);   // [512,512] f32  dead after Xp
    u16*   Xp    = (u16*)(ws + 14155776);     // [8192,512]     live until S done
    u16*   WvT   = (u16*)(ws + 22544384);     // [4096,512]     dead after V GEMM
    u16*   Tb    = (u16*)(ws + 26738688);     // T[bh][512,512] 67.1 MB (dead after S)
    u16*   Ob    = (u16*)(ws + 26738688);     // overlay on T after S
    u16*   Vt    = (u16*)(ws + 93847552);     // Vt[b*8+h][e][t] 67.1 MB
    u16*   WuT   = (u16*)(ws + 93847552);     // overlay on Vt after PV
    u16*   Sb    = (u16*)(ws + 160956416);    // S[bh][512,512] 67.1 MB contiguous
    float* outb  = (float*)(ws + 160956416);  // overlay on S after PV
    float* scb   = (float*)(ws + 177733632);  // [8192]
    float* poolp = (float*)(ws + 177766400);  // [128][512]
    float* pbf   = (float*)(ws + 178028544);  // [16][512]
    float* partK = (float*)(ws + 228065280);  // [2][8192,512] f32, ends 261619712

    // setup
    transpose_cast<<<dim3(16, 16), 256, 0, stream>>>(Wp, WpT, 512, 512);
    transpose_cast<<<dim3(128, 16), 256, 0, stream>>>(Wv, WvT, 512, 4096);
    cast2<<<dim3(2048, 1, 2), 256, 0, stream>>>(Wq, Wk, WqC, WkC);
    pe_fill<<<512, 256, 0, stream>>>(peb);

    // Xp = bf16(x) @ WpT^T + pe     (f32 A, reg-staged cast)
    gemm_bt<0, 1, true><<<dim3(64, 4, 1), 256, 0, stream>>>(
        x, WpT, Xp, peb, 512, 512, 512, 0, 0);

    // MT[h][a'][a] = sum_j Wk[a',h*512+j] * Wq[a,h*512+j]   (2.1 GF, tiny)
    gemm_bt<3><<<dim3(4, 4, 8), 256, 0, stream>>>(
        WkC, WqC, Mbuf, nullptr, 4096, 4096, 512, 512, 512);

    // Vt = (Xp @ Wv)^T per (b,h)  — V-only GEMM, transposed epilogue
    gemm_bt<8, 2><<<dim3(64, 32, 1), 256, 0, stream>>>(
        Xp, WvT, Vt, nullptr, 512, 512, 512, 0, 0);

    // T[bh] = Xp_b @ M_h          (A batch bz>>3, B batch bz&7)
    gemm_bt<3, 0, false, 1, 2><<<dim3(4, 4, 128), 256, 0, stream>>>(
        Xp, Mbuf, Tb, nullptr, 512, 512, 512, 262144, 262144);

    // S[bh] = T[bh] @ Xp_b^T      (B = Xp rows, batch bz>>3)
    gemm_bt<3, 0, false, 0, 1><<<dim3(4, 4, 128), 256, 0, stream>>>(
        Tb, Xp, Sb, nullptr, 512, 512, 512, 262144, 262144);

    // P = softmax(lambda*S) in place (single contiguous buffer)
    softmax_bf16<<<16384, 256, 0, stream>>>(Sb);

    // O[b*t, h*512+e] = P @ V     (B = Vt rows [e][t])
    gemm_bt<6><<<dim3(4, 4, 128), 256, 0, stream>>>(
        Sb, Vt, Ob, nullptr, 512, 512, 512, 262144, 262144);

    // WuT cast (Vt region dead after PV)
    transpose_cast<<<dim3(16, 128), 256, 0, stream>>>(Wu, WuT, 4096, 512);

    // out = O @ Wu + bu : split-K=2 partials, then fused combine+bias+dot
    gemm_bt<7, 1><<<dim3(64, 4, 2), 256, 0, stream>>>(
        Ob, WuT, partK, nullptr, 4096, 4096, 2048, 2048, 2048);
    combine_dot<<<8192, 256, 0, stream>>>(partK, bu, qry, outb, scb);

    // attention pooling
    pool_softmax<<<16, 256, 0, stream>>>(scb, pbf);
    pool_partial<<<dim3(8, 16), 512, 0, stream>>>(outb, pbf, poolp);
    pool_reduce<<<32, 256, 0, stream>>>(poolp, (float*)d_out);
}

// Round 14
// 375.300 us; speedup vs baseline: 1.1161x; 1.0008x over previous
//
#include <hip/hip_runtime.h>
#include <hip/hip_bf16.h>

typedef unsigned short u16;
typedef u16   u16x4  __attribute__((ext_vector_type(4)));
typedef u16   u16x8  __attribute__((ext_vector_type(8)));
typedef float f32x16 __attribute__((ext_vector_type(16)));

// ---------- helpers ----------

__device__ __forceinline__ u16 f2bf(float f) {
    union { float f; unsigned u; } v; v.f = f;
    unsigned u = v.u;
    unsigned r = (u + 0x7fffu + ((u >> 16) & 1u)) >> 16;   // RNE
    return (u16)r;
}
__device__ __forceinline__ float bf2f(u16 u) {
    union { unsigned u; float f; } x; x.u = (unsigned)u << 16; return x.f;
}

// 32x32x16 MFMA (inline asm). A/B: 4 VGPRs = 8 bf16; C/D: 16 f32.
__device__ __forceinline__ void mfma32(f32x16& d, u16x8 a, u16x8 b) {
    asm("v_mfma_f32_32x32x16_bf16 %0, %1, %2, %0" : "+v"(d) : "v"(a), "v"(b));
}

// ---------- unified GEMM: C = A[M,K] * (BT[N,K])^T, bf16 (or f32) in, f32 acc --
// Tile 128x128, BK=64, 256 threads = 4 waves (2x2 of 64x64), 32x32x16 MFMA
// (R10-proven: MfmaUtil 35%, conflicts 3.1e6, 790 TF, VGPR 64).
// R12 lesson: T14 reg-prefetch REVERTED (+12 VGPR -> occupancy 39->30%, net -7%).
// R13: algebraic restructure — S = Xp (WqWk^T) Xp^T; Q/K never materialized.
// NOTE (R6/R8/R10): global_load_lds LDS image follows the address-ordered set,
// not lane order — source-permutation swizzle is a no-op; gload path closed.
// EPI: 0 = +pe(aux by row&511), bf16 out [.,512]           (staged)
//      3 = bf16 out batched: (bz<<18) + row*512+col        (staged)
//      6 = O scatter: bz -> (b=bz>>3, h=bz&7); [8192,4096] (staged)
//      7 = f32 split-K partial: Cv + (bz<<22) + row*512+col (direct)
//      8 = V-transpose: Vt[(b*8+h)][e][t], b=m0>>9, h=n0>>9 (staged)
// SWZ: 1 = bijective flat XCD remap; 2 = 8x8 supertile-per-XCD
// AF32: A operand is f32, cast during staging
// ASEL: A batch index: 0 = bz, 1 = bz>>3
// BSEL: B batch index: 0 = bz, 1 = bz>>3, 2 = bz&7

#define LDK 72

template<int EPI, int SWZ = 0, bool AF32 = false, int ASEL = 0, int BSEL = 0>
__global__ __launch_bounds__(256)
void gemm_bt(const void* __restrict__ Av, const u16* __restrict__ BT,
             void* __restrict__ Cv, const float* __restrict__ aux,
             int lda, int ldb, int K, long sAb, long sBb)
{
    __shared__ u16 smem[2][128 * LDK];   // 36864 B; epilogue cs reuses first 16384 elems
    u16* As = smem[0];
    u16* Bs = smem[1];

    const int tid  = threadIdx.x;
    const int lane = tid & 63;
    const int wid  = tid >> 6;
    const int wm   = wid >> 1, wn = wid & 1;
    const int bz   = blockIdx.z;

    int bx = blockIdx.x, by = blockIdx.y;
    if (SWZ == 1) {
        const int gx = gridDim.x;
        const int n  = gx * gridDim.y;      // must be %8==0
        const int q  = n >> 3;
        int f = by * gx + bx;
        f = (f & 7) * q + (f >> 3);
        bx = f % gx; by = f / gx;
    } else if (SWZ == 2) {                  // 8x8 supertiles, one per XCD
        const int orig = by * gridDim.x + bx;
        const int xcd  = orig & 7;
        const int j    = orig >> 3;
        const int s    = xcd + ((j >> 6) << 3);
        const int t    = j & 63;
        bx = ((s & 7) << 3) + (t & 7);
        by = ((s >> 3) << 3) + (t >> 3);
    }
    const int m0 = bx * 128;
    const int n0 = by * 128;

    const long az = (ASEL == 0) ? bz : (bz >> 3);
    const long bzb = (BSEL == 0) ? bz : (BSEL == 1 ? (bz >> 3) : (bz & 7));
    const u16*   Ab = (const u16*)Av   + az * sAb;
    const float* Af = (const float*)Av + az * sAb;
    const u16*   Bb = BT + bzb * sBb;

    const int tr = tid >> 3;          // 0..31
    const int tc = (tid & 7) << 3;    // 0..56

    f32x16 acc[2][2];
#pragma unroll
    for (int i = 0; i < 2; ++i)
#pragma unroll
        for (int j = 0; j < 2; ++j)
            acc[i][j] = (f32x16){0.f,0.f,0.f,0.f,0.f,0.f,0.f,0.f,
                                 0.f,0.f,0.f,0.f,0.f,0.f,0.f,0.f};

    // VALU-write -> MFMA-srcC hazard fence
    asm volatile("s_nop 3"
        : "+v"(acc[0][0]), "+v"(acc[0][1]), "+v"(acc[1][0]), "+v"(acc[1][1]));

    const int fr = lane & 31;             // A/B operand row within 32-block
    const int q8 = (lane >> 5) << 3;      // k sub-chunk: 0 or 8

    for (int kt = 0; kt < K; kt += 64) {
        __syncthreads();
#pragma unroll
        for (int j = 0; j < 4; ++j) {
            const int r = tr + 32 * j;
            if (AF32) {
                const float* pa = &Af[(size_t)(m0 + r) * lda + kt + tc];
                float4 f0 = *(const float4*)pa;
                float4 f1 = *(const float4*)(pa + 4);
                u16x8 w = { f2bf(f0.x), f2bf(f0.y), f2bf(f0.z), f2bf(f0.w),
                            f2bf(f1.x), f2bf(f1.y), f2bf(f1.z), f2bf(f1.w) };
                *(u16x8*)&As[r * LDK + tc] = w;
            } else {
                *(u16x8*)&As[r * LDK + tc] = *(const u16x8*)&Ab[(size_t)(m0 + r) * lda + kt + tc];
            }
            *(u16x8*)&Bs[r * LDK + tc] = *(const u16x8*)&Bb[(size_t)(n0 + r) * ldb + kt + tc];
        }
        __syncthreads();

#pragma unroll
        for (int ks = 0; ks < 4; ++ks) {
            const int ko = ks * 16 + q8;
            u16x8 a0 = *(const u16x8*)&As[(wm * 64 +      fr) * LDK + ko];
            u16x8 a1 = *(const u16x8*)&As[(wm * 64 + 32 + fr) * LDK + ko];
            u16x8 b0 = *(const u16x8*)&Bs[(wn * 64 +      fr) * LDK + ko];
            u16x8 b1 = *(const u16x8*)&Bs[(wn * 64 + 32 + fr) * LDK + ko];
            mfma32(acc[0][0], a0, b0);
            mfma32(acc[0][1], a0, b1);
            mfma32(acc[1][0], a1, b0);
            mfma32(acc[1][1], a1, b1);
        }
    }

    // MFMA-write -> VALU/VMEM-read hazard fence
    asm volatile("s_nop 7\n\ts_nop 7\n\ts_nop 7"
        : "+v"(acc[0][0]), "+v"(acc[0][1]), "+v"(acc[1][0]), "+v"(acc[1][1]));

    // C/D map (m74/m101): col = lane&31, row = (reg&3) + 8*(reg>>2) + 4*(lane>>5)
    const int lc = lane & 31;
    const int lq = (lane >> 5) << 2;

    if (EPI == 7) {   // direct f32 split-K partial
#pragma unroll
        for (int mi = 0; mi < 2; ++mi)
#pragma unroll
            for (int ni = 0; ni < 2; ++ni)
#pragma unroll
                for (int i = 0; i < 16; ++i) {
                    const int row = m0 + wm * 64 + mi * 32 + (i & 3) + 8 * (i >> 2) + lq;
                    const int col = n0 + wn * 64 + ni * 32 + lc;
                    ((float*)Cv)[((size_t)bz << 22) + (size_t)row * 512 + col] = acc[mi][ni][i];
                }
        return;
    }

    // staged bf16 epilogue via cs[128][128] (XOR-swizzled; R4-proven)
    u16* cs = (u16*)smem;
    auto cswz = [](int r, int c) { return r * 128 + (c ^ (((r >> 3) & 7) << 4)); };
    __syncthreads();
#pragma unroll
    for (int mi = 0; mi < 2; ++mi)
#pragma unroll
        for (int ni = 0; ni < 2; ++ni)
#pragma unroll
            for (int i = 0; i < 16; ++i) {
                const int rl = wm * 64 + mi * 32 + (i & 3) + 8 * (i >> 2) + lq;
                const int cl = wn * 64 + ni * 32 + lc;
                float v = acc[mi][ni][i];
                if (EPI == 0) v += aux[(((m0 + rl) & 511) << 9) + n0 + cl];
                cs[cswz(rl, cl)] = f2bf(v);
            }
    __syncthreads();

    if (EPI == 8) {
        // V written transposed -> Vt[(b*8+h)][e][t]
        const int elq = tid >> 4;          // 0..15
        const int t8  = (tid & 15) << 3;   // 0..120
        const int hh  = n0 >> 9;
        const int bb  = m0 >> 9;
        const int e0v = n0 & 511;
        const int t0v = m0 & 511;
#pragma unroll
        for (int q = 0; q < 8; ++q) {
            const int e_loc = q * 16 + elq;
            u16x8 w;
#pragma unroll
            for (int k = 0; k < 8; ++k) w[k] = cs[cswz(t8 + k, e_loc)];
            const size_t dst = ((size_t)(bb * 8 + hh) << 18)
                             + (size_t)(e0v + e_loc) * 512 + t0v + t8;
            *(u16x8*)&((u16*)Cv)[dst] = w;
        }
        return;
    }

    const int frl = tid >> 4;          // 0..15
    const int fc8 = (tid & 15) << 3;   // 0..120
#pragma unroll
    for (int p = 0; p < 8; ++p) {
        const int rl = p * 16 + frl;
        u16x8 w = *(u16x8*)&cs[rl * 128 + (fc8 ^ (((rl >> 3) & 7) << 4))];
        const int row = m0 + rl;
        const int col = n0 + fc8;
        size_t dst;
        if (EPI == 0) {
            dst = (size_t)row * 512 + col;
        } else if (EPI == 3) {
            dst = ((size_t)bz << 18) + ((size_t)row << 9) + col;
        } else {                       // EPI 6: O scatter, bz -> (b,h)
            const int bb = bz >> 3;
            const int hh = bz & 7;
            dst = ((size_t)(bb * 512 + row)) * 4096 + hh * 512 + col;
        }
        *(u16x8*)&((u16*)Cv)[dst] = w;
    }
}

// ---------- small kernels ----------

// fp32 [R,C] -> bf16 [C,R]
__global__ __launch_bounds__(256)
void transpose_cast(const float* __restrict__ in, u16* __restrict__ out, int R, int C) {
    __shared__ float t[32][33];
    const int tx = threadIdx.x & 31, ty = threadIdx.x >> 5;
    const int c0 = blockIdx.x * 32, r0 = blockIdx.y * 32;
#pragma unroll
    for (int j = 0; j < 4; ++j)
        t[ty + 8 * j][tx] = in[(size_t)(r0 + ty + 8 * j) * C + c0 + tx];
    __syncthreads();
#pragma unroll
    for (int j = 0; j < 4; ++j)
        out[(size_t)(c0 + ty + 8 * j) * R + r0 + tx] = f2bf(t[tx][ty + 8 * j]);
}

// straight casts: z=0 Wq->WqC, z=1 Wk->WkC  ([512,4096] f32 -> bf16, same layout)
__global__ __launch_bounds__(256)
void cast2(const float* __restrict__ a, const float* __restrict__ b,
           u16* __restrict__ oa, u16* __restrict__ ob) {
    const float* in = blockIdx.z == 0 ? a : b;
    u16* o = blockIdx.z == 0 ? oa : ob;
    const int i = blockIdx.x * 256 + threadIdx.x;   // 524288 f32x4 groups
    float4 v = ((const float4*)in)[i];
    u16x4 w = { f2bf(v.x), f2bf(v.y), f2bf(v.z), f2bf(v.w) };
    ((u16x4*)o)[i] = w;
}

__global__ __launch_bounds__(256)
void pe_fill(float* __restrict__ pe) {
    const int idx = blockIdx.x * 256 + threadIdx.x;   // 512 pos x 256 freq-pairs
    const int p = idx >> 8, i2 = idx & 255;
    const float div = expf((float)(2 * i2) * -0.017988946039015984f);  // -ln(10000)/512
    const float arg = (float)p * div;
    pe[(p << 9) + 2 * i2]     = sinf(arg);
    pe[(p << 9) + 2 * i2 + 1] = cosf(arg);
}

__global__ __launch_bounds__(256)
void diag_fill(float* __restrict__ out, int n, float val) {
    const int i = blockIdx.x * 256 + threadIdx.x;
    if (i < n) out[i] = val;
}

// in-place row softmax of lambda*S, bf16; 4 rows per 256-thread block
__global__ __launch_bounds__(256)
void softmax_bf16(u16* __restrict__ S) {
    const size_t row = (size_t)blockIdx.x * 4 + (threadIdx.x >> 6);
    const int lane = threadIdx.x & 63;
    u16* p = S + (row << 9) + lane * 8;
    u16x8 w = *(u16x8*)p;
    float v[8];
#pragma unroll
    for (int j = 0; j < 8; ++j) v[j] = bf2f(w[j]);
    float m = fmaxf(fmaxf(fmaxf(v[0], v[1]), fmaxf(v[2], v[3])),
                    fmaxf(fmaxf(v[4], v[5]), fmaxf(v[6], v[7])));
#pragma unroll
    for (int o = 32; o > 0; o >>= 1) m = fmaxf(m, __shfl_xor(m, o, 64));
    const float lam = 0.044194173824159216f;   // 512^-0.5
    float s = 0.f;
#pragma unroll
    for (int j = 0; j < 8; ++j) { v[j] = __expf((v[j] - m) * lam); s += v[j]; }
#pragma unroll
    for (int o = 32; o > 0; o >>= 1) s += __shfl_xor(s, o, 64);
    const float inv = 1.0f / s;
#pragma unroll
    for (int j = 0; j < 8; ++j) w[j] = f2bf(v[j] * inv);
    *(u16x8*)p = w;
}

// split-K combine + bias + pooling-score dot, one block per token row
__global__ __launch_bounds__(256)
void combine_dot(const float* __restrict__ pk, const float* __restrict__ bu,
                 const float* __restrict__ qry, float* __restrict__ outb,
                 float* __restrict__ sc) {
    const int row = blockIdx.x, t = threadIdx.x;
    const size_t b0 = (size_t)row * 512;
    float o0 = pk[b0 + t]       + pk[b0 + t + 4194304]       + bu[t];
    float o1 = pk[b0 + t + 256] + pk[b0 + t + 256 + 4194304] + bu[t + 256];
    outb[b0 + t]       = o0;
    outb[b0 + t + 256] = o1;
    float acc = o0 * qry[t] + o1 * qry[t + 256];
    const int lane = t & 63, wid = t >> 6;
    __shared__ float red[4];
#pragma unroll
    for (int o = 32; o > 0; o >>= 1) acc += __shfl_xor(acc, o, 64);
    if (lane == 0) red[wid] = acc;
    __syncthreads();
    if (t == 0) sc[row] = red[0] + red[1] + red[2] + red[3];
}

__global__ __launch_bounds__(256)
void pool_softmax(const float* __restrict__ sc, float* __restrict__ p) {
    const int b = blockIdx.x, tid = threadIdx.x;
    const int lane = tid & 63, wid = tid >> 6;
    __shared__ float red[8];
    float v0 = sc[(b << 9) + tid];
    float v1 = sc[(b << 9) + 256 + tid];
    float m = fmaxf(v0, v1);
#pragma unroll
    for (int o = 32; o > 0; o >>= 1) m = fmaxf(m, __shfl_xor(m, o, 64));
    if (lane == 0) red[wid] = m;
    __syncthreads();
    m = fmaxf(fmaxf(red[0], red[1]), fmaxf(red[2], red[3]));
    float e0 = __expf(v0 - m), e1 = __expf(v1 - m);
    float s = e0 + e1;
#pragma unroll
    for (int o = 32; o > 0; o >>= 1) s += __shfl_xor(s, o, 64);
    if (lane == 0) red[4 + wid] = s;
    __syncthreads();
    s = red[4] + red[5] + red[6] + red[7];
    const float inv = 1.0f / s;
    p[(b << 9) + tid]       = e0 * inv;
    p[(b << 9) + 256 + tid] = e1 * inv;
}

// partial pooled sums over t-slices of 64
__global__ __launch_bounds__(512)
void pool_partial(const float* __restrict__ outb, const float* __restrict__ p,
                  float* __restrict__ part) {
    const int ts = blockIdx.x, b = blockIdx.y, e = threadIdx.x;
    float acc = 0.f;
#pragma unroll 8
    for (int tt = 0; tt < 64; ++tt) {
        const int t = ts * 64 + tt;
        acc += p[(b << 9) + t] * outb[((size_t)(b * 512 + t) << 9) + e];
    }
    part[((size_t)(ts * 16 + b) << 9) + e] = acc;
}

__global__ __launch_bounds__(256)
void pool_reduce(const float* __restrict__ part, float* __restrict__ dout) {
    const int i = blockIdx.x * 256 + threadIdx.x;  // 8192
    const int b = i >> 9, e = i & 511;
    float acc = 0.f;
#pragma unroll
    for (int ts = 0; ts < 8; ++ts) acc += part[((size_t)(ts * 16 + b) << 9) + e];
    dout[i] = acc;
}

// ---------- launch ----------

extern "C" void kernel_launch(void* const* d_in, const int* in_sizes, int n_in,
                              void* d_out, int out_size, void* d_ws, size_t ws_size,
                              hipStream_t stream)
{
    (void)in_sizes; (void)n_in;
    const float* x   = (const float*)d_in[0];
    const float* Wp  = (const float*)d_in[1];
    const float* Wk  = (const float*)d_in[2];   // dict order: W_k BEFORE W_q!
    const float* Wq  = (const float*)d_in[3];
    const float* Wv  = (const float*)d_in[4];
    const float* Wu  = (const float*)d_in[5];
    const float* bu  = (const float*)d_in[6];
    const float* qry = (const float*)d_in[7];

    char* ws = (char*)d_ws;
    const size_t NEED = 261619712ull;   // fits 256 MiB budget
    if (ws_size < NEED) {
        diag_fill<<<(out_size + 255) / 256, 256, 0, stream>>>(
            (float*)d_out, out_size, (float)(ws_size >> 20));
        return;
    }

    // ---- byte-offset layout (lifetime-overlaid) ----
    u16*   WpT   = (u16*)(ws + 0);            // [512,512]      dead after Xp
    u16*   WqC   = (u16*)(ws + 524288);       // [512,4096] bf16, straight cast
    u16*   WkC   = (u16*)(ws + 4718592);      // [512,4096] bf16
    u16*   Mbuf  = (u16*)(ws + 8912896);      // MT[h][512,512] bf16, 4 MiB
    float* peb   = (float*)(ws + 13107200);   // [512,512] f32  dead after Xp
    u16*   Xp    = (u16*)(ws + 14155776);     // [8192,512]     live until S done
    u16*   WvT   = (u16*)(ws + 22544384);     // [4096,512]     dead after V GEMM
    u16*   Tb    = (u16*)(ws + 26738688);     // T[bh][512,512] 67.1 MB (dead after S)
    u16*   Ob    = (u16*)(ws + 26738688);     // overlay on T after S
    u16*   Vt    = (u16*)(ws + 93847552);     // Vt[b*8+h][e][t] 67.1 MB
    u16*   WuT   = (u16*)(ws + 93847552);     // overlay on Vt after PV
    u16*   Sb    = (u16*)(ws + 160956416);    // S[bh][512,512] 67.1 MB contiguous
    float* outb  = (float*)(ws + 160956416);  // overlay on S after PV
    float* scb   = (float*)(ws + 177733632);  // [8192]
    float* poolp = (float*)(ws + 177766400);  // [128][512]
    float* pbf   = (float*)(ws + 178028544);  // [16][512]
    float* partK = (float*)(ws + 228065280);  // [2][8192,512] f32, ends 261619712

    // setup
    transpose_cast<<<dim3(16, 16), 256, 0, stream>>>(Wp, WpT, 512, 512);
    transpose_cast<<<dim3(128, 16), 256, 0, stream>>>(Wv, WvT, 512, 4096);
    cast2<<<dim3(2048, 1, 2), 256, 0, stream>>>(Wq, Wk, WqC, WkC);
    pe_fill<<<512, 256, 0, stream>>>(peb);

    // Xp = bf16(x) @ WpT^T + pe     (f32 A, reg-staged cast)
    gemm_bt<0, 1, true><<<dim3(64, 4, 1), 256, 0, stream>>>(
        x, WpT, Xp, peb, 512, 512, 512, 0, 0);

    // MT[h][a'][a] = sum_j Wk[a',h*512+j] * Wq[a,h*512+j]   (2.1 GF, tiny)
    gemm_bt<3><<<dim3(4, 4, 8), 256, 0, stream>>>(
        WkC, WqC, Mbuf, nullptr, 4096, 4096, 512, 512, 512);

    // Vt = (Xp @ Wv)^T per (b,h)  — V-only GEMM, transposed epilogue
    gemm_bt<8, 2><<<dim3(64, 32, 1), 256, 0, stream>>>(
        Xp, WvT, Vt, nullptr, 512, 512, 512, 0, 0);

    // T[bh] = Xp_b @ M_h          (A batch bz>>3, B batch bz&7)
    gemm_bt<3, 0, false, 1, 2><<<dim3(4, 4, 128), 256, 0, stream>>>(
        Xp, Mbuf, Tb, nullptr, 512, 512, 512, 262144, 262144);

    // S[bh] = T[bh] @ Xp_b^T      (B = Xp rows, batch bz>>3)
    gemm_bt<3, 0, false, 0, 1><<<dim3(4, 4, 128), 256, 0, stream>>>(
        Tb, Xp, Sb, nullptr, 512, 512, 512, 262144, 262144);

    // P = softmax(lambda*S) in place (single contiguous buffer)
    softmax_bf16<<<16384, 256, 0, stream>>>(Sb);

    // O[b*t, h*512+e] = P @ V     (B = Vt rows [e][t])
    gemm_bt<6><<<dim3(4, 4, 128), 256, 0, stream>>>(
        Sb, Vt, Ob, nullptr, 512, 512, 512, 262144, 262144);

    // WuT cast (Vt region dead after PV)
    transpose_cast<<<dim3(16, 128), 256, 0, stream>>>(Wu, WuT, 4096, 512);

    // out = O @ Wu + bu : split-K=2 partials, then fused combine+bias+dot
    gemm_bt<7, 1><<<dim3(64, 4, 2), 256, 0, stream>>>(
        Ob, WuT, partK, nullptr, 4096, 4096, 2048, 2048, 2048);
    combine_dot<<<8192, 256, 0, stream>>>(partK, bu, qry, outb, scb);

    // attention pooling
    pool_softmax<<<16, 256, 0, stream>>>(scb, pbf);
    pool_partial<<<dim3(8, 16), 512, 0, stream>>>(outb, pbf, poolp);
    pool_reduce<<<32, 256, 0, stream>>>(poolp, (float*)d_out);
}

// Round 15
// 350.418 us; speedup vs baseline: 1.1953x; 1.0710x over previous
//
#include <hip/hip_runtime.h>
#include <hip/hip_bf16.h>

typedef unsigned short u16;
typedef u16   u16x4  __attribute__((ext_vector_type(4)));
typedef u16   u16x8  __attribute__((ext_vector_type(8)));
typedef float f32x16 __attribute__((ext_vector_type(16)));

// ---------- helpers ----------

__device__ __forceinline__ u16 f2bf(float f) {
    union { float f; unsigned u; } v; v.f = f;
    unsigned u = v.u;
    unsigned r = (u + 0x7fffu + ((u >> 16) & 1u)) >> 16;   // RNE
    return (u16)r;
}
__device__ __forceinline__ float bf2f(u16 u) {
    union { unsigned u; float f; } x; x.u = (unsigned)u << 16; return x.f;
}

// 32x32x16 MFMA (inline asm). A/B: 4 VGPRs = 8 bf16; C/D: 16 f32.
__device__ __forceinline__ void mfma32(f32x16& d, u16x8 a, u16x8 b) {
    asm("v_mfma_f32_32x32x16_bf16 %0, %1, %2, %0" : "+v"(d) : "v"(a), "v"(b));
}

// ---------- unified GEMM: C = A[M,K] * (BT[N,K])^T, bf16 (or f32) in, f32 acc --
// Tile 128x128, BK=64, 256 threads = 4 waves (2x2 of 64x64), 32x32x16 MFMA
// (R10-proven: MfmaUtil 35%, conflicts ~0, 790 TF, VGPR 64).
// R12 lesson: T14 reg-prefetch REVERTED (+12 VGPR -> occupancy 39->30%, net -7%).
// R13: algebraic restructure — S = Xp (WqWk^T) Xp^T; Q/K never materialized.
// R15: SWZ=3 z-slice XCD clustering for batched z=128 GEMMs (R14 showed them
// latency-bound: MfmaUtil 18%, FETCH 2.7x ideal — slices scattered over XCDs).
// NOTE (R6/R8/R10): global_load_lds LDS image follows the address-ordered set,
// not lane order — source-permutation swizzle is a no-op; gload path closed.
// EPI: 0 = +pe(aux by row&511), bf16 out [.,512]           (staged)
//      3 = bf16 out batched: (bz<<18) + row*512+col        (staged)
//      6 = O scatter: bz -> (b=bz>>3, h=bz&7); [8192,4096] (staged)
//      7 = f32 split-K partial: Cv + (bz<<22) + row*512+col (direct)
//      8 = V-transpose: Vt[(b*8+h)][e][t], b=m0>>9, h=n0>>9 (staged)
// SWZ: 1 = bijective flat XCD remap; 2 = 8x8 supertile-per-XCD;
//      3 = z-slice clustering: each XCD owns gridDim.z/8 CONTIGUOUS z-slices
//          (all 16 tiles of a slice on one XCD; consecutive slices share Xp_b)
// AF32: A operand is f32, cast during staging
// ASEL: A batch index: 0 = bz, 1 = bz>>3
// BSEL: B batch index: 0 = bz, 1 = bz>>3, 2 = bz&7

#define LDK 72

template<int EPI, int SWZ = 0, bool AF32 = false, int ASEL = 0, int BSEL = 0>
__global__ __launch_bounds__(256)
void gemm_bt(const void* __restrict__ Av, const u16* __restrict__ BT,
             void* __restrict__ Cv, const float* __restrict__ aux,
             int lda, int ldb, int K, long sAb, long sBb)
{
    __shared__ u16 smem[2][128 * LDK];   // 36864 B; epilogue cs reuses first 16384 elems
    u16* As = smem[0];
    u16* Bs = smem[1];

    const int tid  = threadIdx.x;
    const int lane = tid & 63;
    const int wid  = tid >> 6;
    const int wm   = wid >> 1, wn = wid & 1;

    int bx = blockIdx.x, by = blockIdx.y, bz = blockIdx.z;
    if (SWZ == 1) {
        const int gx = gridDim.x;
        const int n  = gx * gridDim.y;      // must be %8==0
        const int q  = n >> 3;
        int f = by * gx + bx;
        f = (f & 7) * q + (f >> 3);
        bx = f % gx; by = f / gx;
    } else if (SWZ == 2) {                  // 8x8 supertiles, one per XCD
        const int orig = by * gridDim.x + bx;
        const int xcd  = orig & 7;
        const int j    = orig >> 3;
        const int s    = xcd + ((j >> 6) << 3);
        const int t    = j & 63;
        bx = ((s & 7) << 3) + (t & 7);
        by = ((s >> 3) << 3) + (t >> 3);
    } else if (SWZ == 3) {                  // z-slice clustering (gridDim.z%8==0)
        const int gx = gridDim.x, gy = gridDim.y;
        const int tiles = gx * gy;          // blocks per z-slice
        const int f = (bz * gy + by) * gx + bx;
        const int xcd = f & 7;
        const int j = f >> 3;
        const int perx = gridDim.z >> 3;    // slices per XCD
        const int g = j / tiles;
        const int t = j - g * tiles;
        bz = xcd * perx + g;
        by = t / gx;
        bx = t - by * gx;
    }
    const int m0 = bx * 128;
    const int n0 = by * 128;

    const long az = (ASEL == 0) ? bz : (bz >> 3);
    const long bzb = (BSEL == 0) ? bz : (BSEL == 1 ? (bz >> 3) : (bz & 7));
    const u16*   Ab = (const u16*)Av   + az * sAb;
    const float* Af = (const float*)Av + az * sAb;
    const u16*   Bb = BT + bzb * sBb;

    const int tr = tid >> 3;          // 0..31
    const int tc = (tid & 7) << 3;    // 0..56

    f32x16 acc[2][2];
#pragma unroll
    for (int i = 0; i < 2; ++i)
#pragma unroll
        for (int j = 0; j < 2; ++j)
            acc[i][j] = (f32x16){0.f,0.f,0.f,0.f,0.f,0.f,0.f,0.f,
                                 0.f,0.f,0.f,0.f,0.f,0.f,0.f,0.f};

    // VALU-write -> MFMA-srcC hazard fence
    asm volatile("s_nop 3"
        : "+v"(acc[0][0]), "+v"(acc[0][1]), "+v"(acc[1][0]), "+v"(acc[1][1]));

    const int fr = lane & 31;             // A/B operand row within 32-block
    const int q8 = (lane >> 5) << 3;      // k sub-chunk: 0 or 8

    for (int kt = 0; kt < K; kt += 64) {
        __syncthreads();
#pragma unroll
        for (int j = 0; j < 4; ++j) {
            const int r = tr + 32 * j;
            if (AF32) {
                const float* pa = &Af[(size_t)(m0 + r) * lda + kt + tc];
                float4 f0 = *(const float4*)pa;
                float4 f1 = *(const float4*)(pa + 4);
                u16x8 w = { f2bf(f0.x), f2bf(f0.y), f2bf(f0.z), f2bf(f0.w),
                            f2bf(f1.x), f2bf(f1.y), f2bf(f1.z), f2bf(f1.w) };
                *(u16x8*)&As[r * LDK + tc] = w;
            } else {
                *(u16x8*)&As[r * LDK + tc] = *(const u16x8*)&Ab[(size_t)(m0 + r) * lda + kt + tc];
            }
            *(u16x8*)&Bs[r * LDK + tc] = *(const u16x8*)&Bb[(size_t)(n0 + r) * ldb + kt + tc];
        }
        __syncthreads();

#pragma unroll
        for (int ks = 0; ks < 4; ++ks) {
            const int ko = ks * 16 + q8;
            u16x8 a0 = *(const u16x8*)&As[(wm * 64 +      fr) * LDK + ko];
            u16x8 a1 = *(const u16x8*)&As[(wm * 64 + 32 + fr) * LDK + ko];
            u16x8 b0 = *(const u16x8*)&Bs[(wn * 64 +      fr) * LDK + ko];
            u16x8 b1 = *(const u16x8*)&Bs[(wn * 64 + 32 + fr) * LDK + ko];
            mfma32(acc[0][0], a0, b0);
            mfma32(acc[0][1], a0, b1);
            mfma32(acc[1][0], a1, b0);
            mfma32(acc[1][1], a1, b1);
        }
    }

    // MFMA-write -> VALU/VMEM-read hazard fence
    asm volatile("s_nop 7\n\ts_nop 7\n\ts_nop 7"
        : "+v"(acc[0][0]), "+v"(acc[0][1]), "+v"(acc[1][0]), "+v"(acc[1][1]));

    // C/D map (m74/m101): col = lane&31, row = (reg&3) + 8*(reg>>2) + 4*(lane>>5)
    const int lc = lane & 31;
    const int lq = (lane >> 5) << 2;

    if (EPI == 7) {   // direct f32 split-K partial
#pragma unroll
        for (int mi = 0; mi < 2; ++mi)
#pragma unroll
            for (int ni = 0; ni < 2; ++ni)
#pragma unroll
                for (int i = 0; i < 16; ++i) {
                    const int row = m0 + wm * 64 + mi * 32 + (i & 3) + 8 * (i >> 2) + lq;
                    const int col = n0 + wn * 64 + ni * 32 + lc;
                    ((float*)Cv)[((size_t)bz << 22) + (size_t)row * 512 + col] = acc[mi][ni][i];
                }
        return;
    }

    // staged bf16 epilogue via cs[128][128] (XOR-swizzled; R4-proven)
    u16* cs = (u16*)smem;
    auto cswz = [](int r, int c) { return r * 128 + (c ^ (((r >> 3) & 7) << 4)); };
    __syncthreads();
#pragma unroll
    for (int mi = 0; mi < 2; ++mi)
#pragma unroll
        for (int ni = 0; ni < 2; ++ni)
#pragma unroll
            for (int i = 0; i < 16; ++i) {
                const int rl = wm * 64 + mi * 32 + (i & 3) + 8 * (i >> 2) + lq;
                const int cl = wn * 64 + ni * 32 + lc;
                float v = acc[mi][ni][i];
                if (EPI == 0) v += aux[(((m0 + rl) & 511) << 9) + n0 + cl];
                cs[cswz(rl, cl)] = f2bf(v);
            }
    __syncthreads();

    if (EPI == 8) {
        // V written transposed -> Vt[(b*8+h)][e][t]
        const int elq = tid >> 4;          // 0..15
        const int t8  = (tid & 15) << 3;   // 0..120
        const int hh  = n0 >> 9;
        const int bb  = m0 >> 9;
        const int e0v = n0 & 511;
        const int t0v = m0 & 511;
#pragma unroll
        for (int q = 0; q < 8; ++q) {
            const int e_loc = q * 16 + elq;
            u16x8 w;
#pragma unroll
            for (int k = 0; k < 8; ++k) w[k] = cs[cswz(t8 + k, e_loc)];
            const size_t dst = ((size_t)(bb * 8 + hh) << 18)
                             + (size_t)(e0v + e_loc) * 512 + t0v + t8;
            *(u16x8*)&((u16*)Cv)[dst] = w;
        }
        return;
    }

    const int frl = tid >> 4;          // 0..15
    const int fc8 = (tid & 15) << 3;   // 0..120
#pragma unroll
    for (int p = 0; p < 8; ++p) {
        const int rl = p * 16 + frl;
        u16x8 w = *(u16x8*)&cs[rl * 128 + (fc8 ^ (((rl >> 3) & 7) << 4))];
        const int row = m0 + rl;
        const int col = n0 + fc8;
        size_t dst;
        if (EPI == 0) {
            dst = (size_t)row * 512 + col;
        } else if (EPI == 3) {
            dst = ((size_t)bz << 18) + ((size_t)row << 9) + col;
        } else {                       // EPI 6: O scatter, bz -> (b,h)
            const int bb = bz >> 3;
            const int hh = bz & 7;
            dst = ((size_t)(bb * 512 + row)) * 4096 + hh * 512 + col;
        }
        *(u16x8*)&((u16*)Cv)[dst] = w;
    }
}

// ---------- small kernels ----------

// fp32 [R,C] -> bf16 [C,R]
__global__ __launch_bounds__(256)
void transpose_cast(const float* __restrict__ in, u16* __restrict__ out, int R, int C) {
    __shared__ float t[32][33];
    const int tx = threadIdx.x & 31, ty = threadIdx.x >> 5;
    const int c0 = blockIdx.x * 32, r0 = blockIdx.y * 32;
#pragma unroll
    for (int j = 0; j < 4; ++j)
        t[ty + 8 * j][tx] = in[(size_t)(r0 + ty + 8 * j) * C + c0 + tx];
    __syncthreads();
#pragma unroll
    for (int j = 0; j < 4; ++j)
        out[(size_t)(c0 + ty + 8 * j) * R + r0 + tx] = f2bf(t[tx][ty + 8 * j]);
}

// straight casts: z=0 Wq->WqC, z=1 Wk->WkC  ([512,4096] f32 -> bf16, same layout)
__global__ __launch_bounds__(256)
void cast2(const float* __restrict__ a, const float* __restrict__ b,
           u16* __restrict__ oa, u16* __restrict__ ob) {
    const float* in = blockIdx.z == 0 ? a : b;
    u16* o = blockIdx.z == 0 ? oa : ob;
    const int i = blockIdx.x * 256 + threadIdx.x;   // 524288 f32x4 groups
    float4 v = ((const float4*)in)[i];
    u16x4 w = { f2bf(v.x), f2bf(v.y), f2bf(v.z), f2bf(v.w) };
    ((u16x4*)o)[i] = w;
}

__global__ __launch_bounds__(256)
void pe_fill(float* __restrict__ pe) {
    const int idx = blockIdx.x * 256 + threadIdx.x;   // 512 pos x 256 freq-pairs
    const int p = idx >> 8, i2 = idx & 255;
    const float div = expf((float)(2 * i2) * -0.017988946039015984f);  // -ln(10000)/512
    const float arg = (float)p * div;
    pe[(p << 9) + 2 * i2]     = sinf(arg);
    pe[(p << 9) + 2 * i2 + 1] = cosf(arg);
}

__global__ __launch_bounds__(256)
void diag_fill(float* __restrict__ out, int n, float val) {
    const int i = blockIdx.x * 256 + threadIdx.x;
    if (i < n) out[i] = val;
}

// in-place row softmax of lambda*S, bf16; 4 rows per 256-thread block
__global__ __launch_bounds__(256)
void softmax_bf16(u16* __restrict__ S) {
    const size_t row = (size_t)blockIdx.x * 4 + (threadIdx.x >> 6);
    const int lane = threadIdx.x & 63;
    u16* p = S + (row << 9) + lane * 8;
    u16x8 w = *(u16x8*)p;
    float v[8];
#pragma unroll
    for (int j = 0; j < 8; ++j) v[j] = bf2f(w[j]);
    float m = fmaxf(fmaxf(fmaxf(v[0], v[1]), fmaxf(v[2], v[3])),
                    fmaxf(fmaxf(v[4], v[5]), fmaxf(v[6], v[7])));
#pragma unroll
    for (int o = 32; o > 0; o >>= 1) m = fmaxf(m, __shfl_xor(m, o, 64));
    const float lam = 0.044194173824159216f;   // 512^-0.5
    float s = 0.f;
#pragma unroll
    for (int j = 0; j < 8; ++j) { v[j] = __expf((v[j] - m) * lam); s += v[j]; }
#pragma unroll
    for (int o = 32; o > 0; o >>= 1) s += __shfl_xor(s, o, 64);
    const float inv = 1.0f / s;
#pragma unroll
    for (int j = 0; j < 8; ++j) w[j] = f2bf(v[j] * inv);
    *(u16x8*)p = w;
}

// split-K combine + bias + pooling-score dot, one block per token row
__global__ __launch_bounds__(256)
void combine_dot(const float* __restrict__ pk, const float* __restrict__ bu,
                 const float* __restrict__ qry, float* __restrict__ outb,
                 float* __restrict__ sc) {
    const int row = blockIdx.x, t = threadIdx.x;
    const size_t b0 = (size_t)row * 512;
    float o0 = pk[b0 + t]       + pk[b0 + t + 4194304]       + bu[t];
    float o1 = pk[b0 + t + 256] + pk[b0 + t + 256 + 4194304] + bu[t + 256];
    outb[b0 + t]       = o0;
    outb[b0 + t + 256] = o1;
    float acc = o0 * qry[t] + o1 * qry[t + 256];
    const int lane = t & 63, wid = t >> 6;
    __shared__ float red[4];
#pragma unroll
    for (int o = 32; o > 0; o >>= 1) acc += __shfl_xor(acc, o, 64);
    if (lane == 0) red[wid] = acc;
    __syncthreads();
    if (t == 0) sc[row] = red[0] + red[1] + red[2] + red[3];
}

__global__ __launch_bounds__(256)
void pool_softmax(const float* __restrict__ sc, float* __restrict__ p) {
    const int b = blockIdx.x, tid = threadIdx.x;
    const int lane = tid & 63, wid = tid >> 6;
    __shared__ float red[8];
    float v0 = sc[(b << 9) + tid];
    float v1 = sc[(b << 9) + 256 + tid];
    float m = fmaxf(v0, v1);
#pragma unroll
    for (int o = 32; o > 0; o >>= 1) m = fmaxf(m, __shfl_xor(m, o, 64));
    if (lane == 0) red[wid] = m;
    __syncthreads();
    m = fmaxf(fmaxf(red[0], red[1]), fmaxf(red[2], red[3]));
    float e0 = __expf(v0 - m), e1 = __expf(v1 - m);
    float s = e0 + e1;
#pragma unroll
    for (int o = 32; o > 0; o >>= 1) s += __shfl_xor(s, o, 64);
    if (lane == 0) red[4 + wid] = s;
    __syncthreads();
    s = red[4] + red[5] + red[6] + red[7];
    const float inv = 1.0f / s;
    p[(b << 9) + tid]       = e0 * inv;
    p[(b << 9) + 256 + tid] = e1 * inv;
}

// partial pooled sums over t-slices of 64
__global__ __launch_bounds__(512)
void pool_partial(const float* __restrict__ outb, const float* __restrict__ p,
                  float* __restrict__ part) {
    const int ts = blockIdx.x, b = blockIdx.y, e = threadIdx.x;
    float acc = 0.f;
#pragma unroll 8
    for (int tt = 0; tt < 64; ++tt) {
        const int t = ts * 64 + tt;
        acc += p[(b << 9) + t] * outb[((size_t)(b * 512 + t) << 9) + e];
    }
    part[((size_t)(ts * 16 + b) << 9) + e] = acc;
}

__global__ __launch_bounds__(256)
void pool_reduce(const float* __restrict__ part, float* __restrict__ dout) {
    const int i = blockIdx.x * 256 + threadIdx.x;  // 8192
    const int b = i >> 9, e = i & 511;
    float acc = 0.f;
#pragma unroll
    for (int ts = 0; ts < 8; ++ts) acc += part[((size_t)(ts * 16 + b) << 9) + e];
    dout[i] = acc;
}

// ---------- launch ----------

extern "C" void kernel_launch(void* const* d_in, const int* in_sizes, int n_in,
                              void* d_out, int out_size, void* d_ws, size_t ws_size,
                              hipStream_t stream)
{
    (void)in_sizes; (void)n_in;
    const float* x   = (const float*)d_in[0];
    const float* Wp  = (const float*)d_in[1];
    const float* Wk  = (const float*)d_in[2];   // dict order: W_k BEFORE W_q!
    const float* Wq  = (const float*)d_in[3];
    const float* Wv  = (const float*)d_in[4];
    const float* Wu  = (const float*)d_in[5];
    const float* bu  = (const float*)d_in[6];
    const float* qry = (const float*)d_in[7];

    char* ws = (char*)d_ws;
    const size_t NEED = 261619712ull;   // fits 256 MiB budget
    if (ws_size < NEED) {
        diag_fill<<<(out_size + 255) / 256, 256, 0, stream>>>(
            (float*)d_out, out_size, (float)(ws_size >> 20));
        return;
    }

    // ---- byte-offset layout (lifetime-overlaid) ----
    u16*   WpT   = (u16*)(ws + 0);            // [512,512]      dead after Xp
    u16*   WqC   = (u16*)(ws + 524288);       // [512,4096] bf16, straight cast
    u16*   WkC   = (u16*)(ws + 4718592);      // [512,4096] bf16
    u16*   Mbuf  = (u16*)(ws + 8912896);      // MT[h][512,512] bf16, 4 MiB
    float* peb   = (float*)(ws + 13107200);   // [512,512] f32  dead after Xp
    u16*   Xp    = (u16*)(ws + 14155776);     // [8192,512]     live until S done
    u16*   WvT   = (u16*)(ws + 22544384);     // [4096,512]     dead after V GEMM
    u16*   Tb    = (u16*)(ws + 26738688);     // T[bh][512,512] 67.1 MB (dead after S)
    u16*   Ob    = (u16*)(ws + 26738688);     // overlay on T after S
    u16*   Vt    = (u16*)(ws + 93847552);     // Vt[b*8+h][e][t] 67.1 MB
    u16*   WuT   = (u16*)(ws + 93847552);     // overlay on Vt after PV
    u16*   Sb    = (u16*)(ws + 160956416);    // S[bh][512,512] 67.1 MB contiguous
    float* outb  = (float*)(ws + 160956416);  // overlay on S after PV
    float* scb   = (float*)(ws + 177733632);  // [8192]
    float* poolp = (float*)(ws + 177766400);  // [128][512]
    float* pbf   = (float*)(ws + 178028544);  // [16][512]
    float* partK = (float*)(ws + 228065280);  // [2][8192,512] f32, ends 261619712

    // setup
    transpose_cast<<<dim3(16, 16), 256, 0, stream>>>(Wp, WpT, 512, 512);
    transpose_cast<<<dim3(128, 16), 256, 0, stream>>>(Wv, WvT, 512, 4096);
    cast2<<<dim3(2048, 1, 2), 256, 0, stream>>>(Wq, Wk, WqC, WkC);
    pe_fill<<<512, 256, 0, stream>>>(peb);

    // Xp = bf16(x) @ WpT^T + pe     (f32 A, reg-staged cast)
    gemm_bt<0, 1, true><<<dim3(64, 4, 1), 256, 0, stream>>>(
        x, WpT, Xp, peb, 512, 512, 512, 0, 0);

    // MT[h][a'][a] = sum_j Wk[a',h*512+j] * Wq[a,h*512+j]   (2.1 GF, tiny)
    gemm_bt<3><<<dim3(4, 4, 8), 256, 0, stream>>>(
        WkC, WqC, Mbuf, nullptr, 4096, 4096, 512, 512, 512);

    // Vt = (Xp @ Wv)^T per (b,h)  — V-only GEMM, transposed epilogue
    gemm_bt<8, 2><<<dim3(64, 32, 1), 256, 0, stream>>>(
        Xp, WvT, Vt, nullptr, 512, 512, 512, 0, 0);

    // T[bh] = Xp_b @ M_h          (A batch bz>>3, B batch bz&7; z-clustered)
    gemm_bt<3, 3, false, 1, 2><<<dim3(4, 4, 128), 256, 0, stream>>>(
        Xp, Mbuf, Tb, nullptr, 512, 512, 512, 262144, 262144);

    // S[bh] = T[bh] @ Xp_b^T      (B = Xp rows, batch bz>>3; z-clustered)
    gemm_bt<3, 3, false, 0, 1><<<dim3(4, 4, 128), 256, 0, stream>>>(
        Tb, Xp, Sb, nullptr, 512, 512, 512, 262144, 262144);

    // P = softmax(lambda*S) in place (single contiguous buffer)
    softmax_bf16<<<16384, 256, 0, stream>>>(Sb);

    // O[b*t, h*512+e] = P @ V     (B = Vt rows [e][t]; z-clustered)
    gemm_bt<6, 3><<<dim3(4, 4, 128), 256, 0, stream>>>(
        Sb, Vt, Ob, nullptr, 512, 512, 512, 262144, 262144);

    // WuT cast (Vt region dead after PV)
    transpose_cast<<<dim3(16, 128), 256, 0, stream>>>(Wu, WuT, 4096, 512);

    // out = O @ Wu + bu : split-K=2 partials, then fused combine+bias+dot
    gemm_bt<7, 1><<<dim3(64, 4, 2), 256, 0, stream>>>(
        Ob, WuT, partK, nullptr, 4096, 4096, 2048, 2048, 2048);
    combine_dot<<<8192, 256, 0, stream>>>(partK, bu, qry, outb, scb);

    // attention pooling
    pool_softmax<<<16, 256, 0, stream>>>(scb, pbf);
    pool_partial<<<dim3(8, 16), 512, 0, stream>>>(outb, pbf, poolp);
    pool_reduce<<<32, 256, 0, stream>>>(poolp, (float*)d_out);
}